// Round 35
// baseline (662.815 us; speedup 1.0000x reference)
//
#include <hip/hip_runtime.h>
#include <hip/hip_bf16.h>
#include <math.h>
#include <stddef.h>

#define BB 32
#define TT 262
#define DD 512
#define SS 16
#define RR 32
#define SEQ 512
#define NV 256
#define PRED 96
#define MROWS (BB*TT)   // 8384
#define NCHK 8
#define CSZ 33          // 8*33 = 264 >= 262

typedef __attribute__((ext_vector_type(4))) float f32x4;
typedef __attribute__((ext_vector_type(8))) short s16x8;

// ---------------- bf16 helpers ----------------
__device__ inline ushort f2bu(float x) {
    __hip_bfloat16 h = __float2bfloat16(x);
    ushort u; __builtin_memcpy(&u, &h, 2); return u;
}
__device__ inline float bu2f(ushort u) {
    __hip_bfloat16 h; __builtin_memcpy(&h, &u, 2);
    return __bfloat162float(h);
}

// async global->LDS, 16B per lane
__device__ inline void gload_lds16(const void* g, void* l) {
    __builtin_amdgcn_global_load_lds(
        (const __attribute__((address_space(1))) void*)g,
        (__attribute__((address_space(3))) void*)l, 16, 0, 0);
}

// ---------------------------------------------------------------------------
// merged weight bf16 cast: all 6 weights in ONE launch.
// ---------------------------------------------------------------------------
__global__ __launch_bounds__(256)
void packall(const float* __restrict__ s0, ushort* __restrict__ d0,  // emb 262144
             const float* __restrict__ s1, ushort* __restrict__ d1,  // win 2097152
             const float* __restrict__ s2, ushort* __restrict__ d2,  // wout 1048576
             const float* __restrict__ s3, ushort* __restrict__ d3,  // ff1 524288
             const float* __restrict__ s4, ushort* __restrict__ d4,  // ff2 524288
             const float* __restrict__ s5, ushort* __restrict__ d5)  // proj 49152
{
    int idx = blockIdx.x * 256 + threadIdx.x;
    const float* s; ushort* dst; int o;
    if      (idx < 262144)  { s = s0; dst = d0; o = idx; }
    else if (idx < 2359296) { s = s1; dst = d1; o = idx - 262144; }
    else if (idx < 3407872) { s = s2; dst = d2; o = idx - 2359296; }
    else if (idx < 3932160) { s = s3; dst = d3; o = idx - 3407872; }
    else if (idx < 4456448) { s = s4; dst = d4; o = idx - 3932160; }
    else if (idx < 4505600) { s = s5; dst = d5; o = idx - 4456448; }
    else return;
    dst[o] = f2bu(s[o]);
}

// ---------------------------------------------------------------------------
// combined scan-projection weight (dt path folded through wdt), bf16
// ---------------------------------------------------------------------------
__global__ __launch_bounds__(256)
void mkcomb(const float* __restrict__ wx, const float* __restrict__ wdt,
            ushort* __restrict__ comb)
{
    int n  = blockIdx.x;
    int li = blockIdx.y;
    const float* wxl = wx + (size_t)li*64*512;
    ushort* outb = comb + ((size_t)li*544 + n)*512;
    if (n < 512) {
        __shared__ float wr[32];
        if (threadIdx.x < 32)
            wr[threadIdx.x] = wdt[(size_t)li*512*32 + (size_t)n*32 + threadIdx.x];
        __syncthreads();
        for (int kk = threadIdx.x; kk < 512; kk += 256) {
            float acc = 0.f;
            #pragma unroll
            for (int r = 0; r < 32; ++r)
                acc = fmaf(wr[r], wxl[r*512 + kk], acc);
            outb[kk] = f2bu(acc);
        }
    } else {
        int s = n - 512;
        for (int kk = threadIdx.x; kk < 512; kk += 256)
            outb[kk] = f2bu(wxl[(32+s)*512 + kk]);
    }
}

// ---------------------------------------------------------------------------
// per-(b,n) mean/std over SEQ. grid = BB*16, block 256 = 16n x 16tg.
// ---------------------------------------------------------------------------
__global__ __launch_bounds__(256)
void stats_kernel(const float* __restrict__ x_enc,
                  float* __restrict__ mean, float* __restrict__ stdv)
{
    int b  = blockIdx.x >> 4;
    int n0 = (blockIdx.x & 15) << 4;
    int nl = threadIdx.x & 15;
    int tg = threadIdx.x >> 4;
    int n = n0 + nl;
    const float* base = x_enc + (size_t)b*SEQ*NV + n;
    float s0 = 0.f, s1 = 0.f, q0 = 0.f, q1 = 0.f;
    #pragma unroll 8
    for (int i = 0; i < 16; ++i) {
        int t = tg + i*32;
        float v0 = base[(size_t)t*NV];
        float v1 = base[(size_t)(t+16)*NV];
        s0 += v0; q0 = fmaf(v0, v0, q0);
        s1 += v1; q1 = fmaf(v1, v1, q1);
    }
    float s = s0 + s1, q = q0 + q1;
    __shared__ float ls[16][17], lq[16][17];
    ls[tg][nl] = s; lq[tg][nl] = q;
    __syncthreads();
    if (tg < 8) { ls[tg][nl] += ls[tg+8][nl]; lq[tg][nl] += lq[tg+8][nl]; }
    __syncthreads();
    if (tg < 4) { ls[tg][nl] += ls[tg+4][nl]; lq[tg][nl] += lq[tg+4][nl]; }
    __syncthreads();
    if (tg < 2) { ls[tg][nl] += ls[tg+2][nl]; lq[tg][nl] += lq[tg+2][nl]; }
    __syncthreads();
    if (tg == 0) {
        s = ls[0][nl] + ls[1][nl];
        q = lq[0][nl] + lq[1][nl];
        float mu  = s * (1.f/SEQ);
        float var = q * (1.f/SEQ) - mu*mu;
        mean[b*NV + n] = mu;
        stdv[b*NV + n] = sqrtf(var + 1e-5f);
    }
}

// ---------------------------------------------------------------------------
// tok: normalized transpose, bf16 rows of 512
// ---------------------------------------------------------------------------
__global__ __launch_bounds__(256)
void tok_kernel(const float* __restrict__ x_enc, const float* __restrict__ x_mark,
                const float* __restrict__ mean, const float* __restrict__ stdv,
                ushort* __restrict__ tokb)
{
    int b  = blockIdx.x / 40;
    int r  = blockIdx.x % 40;
    int tt = r / 5;
    int vt = r % 5;
    int t0 = tt << 6, v0 = vt << 6;
    __shared__ float tile[64][65];
    int lv = threadIdx.x & 63;
    for (int i = threadIdx.x >> 6; i < 64; i += 4) {
        int t = t0 + i, v = v0 + lv;
        float val = 0.f;
        if (v < NV) {
            val = (x_enc[((size_t)b*SEQ + t)*NV + v] - mean[b*NV + v]) / stdv[b*NV + v];
        } else if (v < TT) {
            val = x_mark[((size_t)b*SEQ + t)*6 + (v - NV)];
        }
        tile[i][lv] = val;
    }
    __syncthreads();
    for (int i = threadIdx.x >> 6; i < 64; i += 4) {
        int v = v0 + i;
        if (v < TT) {
            size_t row = (size_t)b*TT + v;
            tokb[row*512 + t0 + lv] = f2bu(tile[lv][i]);
        }
    }
}

// ---------------------------------------------------------------------------
// gemm3: 128x64 tile (kept for N not divisible by 128: comb 544, proj 96).
// ---------------------------------------------------------------------------
template<int HAS_BIAS, int RELU, int WF32, int W3, int SCANEP>
__global__ __launch_bounds__(256)
void gemm3(const ushort* __restrict__ A3, int lda3,
           const ushort* __restrict__ W3p, int ldw3,
           const float* __restrict__ bias,
           float* __restrict__ C, int ldc,
           ushort* __restrict__ C3, int N_out,
           float* __restrict__ bcbuf,
           size_t aOff, size_t wOff, size_t biasOff, size_t cOff, size_t bcOff,
           int M, int Nn, int K3)
{
    const int dir = blockIdx.y;
    A3  += (size_t)dir * aOff;
    W3p += (size_t)dir * wOff;
    if (HAS_BIAS || SCANEP) bias += (size_t)dir * biasOff;
    if (WF32 || SCANEP) C += (size_t)dir * cOff;
    if (SCANEP) bcbuf += (size_t)dir * bcOff;

    __shared__ ushort lds[2][192*64];   // 48 KB
    const int tid  = threadIdx.x;
    const int lane = tid & 63;
    const int wid  = tid >> 6;
    const int wr = wid >> 1, wc = wid & 1;

    int nwg = gridDim.x;
    int q8 = nwg >> 3, r8 = nwg & 7;
    int xcd = blockIdx.x & 7;
    int idx = blockIdx.x >> 3;
    int swz = (xcd < r8 ? xcd*(q8+1) : r8*(q8+1) + (xcd-r8)*q8) + idx;
    int ntile = (Nn + 63) >> 6;
    const int m0 = (swz / ntile) * 128;
    const int n0 = (swz % ntile) * 64;

    const int l8 = lane >> 3;
    const int sl = lane & 7;
    const int ssl = sl ^ l8;

    int arow[4], wrow[2];
    #pragma unroll
    for (int qq = 0; qq < 4; ++qq) {
        int r = (wid*4 + qq)*8 + l8;
        int ar = m0 + r; if (ar > M-1) ar = M-1;
        arow[qq] = ar;
    }
    #pragma unroll
    for (int qq = 0; qq < 2; ++qq) {
        int r = (wid*2 + qq)*8 + l8;
        int wrr = n0 + r; if (wrr > Nn-1) wrr = Nn-1;
        wrow[qq] = wrr;
    }

    f32x4 acc[4][2];
    #pragma unroll
    for (int i = 0; i < 4; ++i)
        #pragma unroll
        for (int j = 0; j < 2; ++j) acc[i][j] = (f32x4){0.f,0.f,0.f,0.f};

    const int nk = K3 >> 6;
    const int rl = lane & 15;
    const int kq = lane >> 4;

    auto stage = [&](int buf_, int kt_) {
        #pragma unroll
        for (int qq = 0; qq < 4; ++qq) {
            int c = wid*4 + qq;
            gload_lds16(A3 + (size_t)arow[qq]*lda3 + kt_*64 + ssl*8,
                        (void*)&lds[buf_][c*512]);
        }
        #pragma unroll
        for (int qq = 0; qq < 2; ++qq) {
            int c = wid*2 + qq;
            gload_lds16(W3p + (size_t)wrow[qq]*ldw3 + kt_*64 + ssl*8,
                        (void*)&lds[buf_][8192 + c*512]);
        }
    };

    stage(0, 0);
    __syncthreads();

    for (int kt = 0; kt < nk; ++kt) {
        int cur = kt & 1;
        if (kt + 1 < nk) stage(cur ^ 1, kt + 1);
        #pragma unroll
        for (int kk = 0; kk < 2; ++kk) {
            s16x8 av[4], wv[2];
            #pragma unroll
            for (int mi = 0; mi < 4; ++mi) {
                int row = wr*64 + mi*16 + rl;
                int ck = (kk*4 + kq) ^ (row & 7);
                av[mi] = *(const s16x8*)&lds[cur][row*64 + (ck<<3)];
            }
            #pragma unroll
            for (int ni = 0; ni < 2; ++ni) {
                int row = wc*32 + ni*16 + rl;
                int ck = (kk*4 + kq) ^ (row & 7);
                wv[ni] = *(const s16x8*)&lds[cur][8192 + row*64 + (ck<<3)];
            }
            #pragma unroll
            for (int mi = 0; mi < 4; ++mi)
                #pragma unroll
                for (int ni = 0; ni < 2; ++ni)
                    acc[mi][ni] = __builtin_amdgcn_mfma_f32_16x16x32_bf16(
                        av[mi], wv[ni], acc[mi][ni], 0, 0, 0);
        }
        __syncthreads();
    }

    #pragma unroll
    for (int ni = 0; ni < 2; ++ni) {
        int n = n0 + wc*32 + ni*16 + rl;
        if (n >= Nn) continue;
        float bv = (HAS_BIAS && !SCANEP) ? bias[n] : 0.f;
        #pragma unroll
        for (int mi = 0; mi < 4; ++mi) {
            #pragma unroll
            for (int j = 0; j < 4; ++j) {
                int m = m0 + wr*64 + mi*16 + kq*4 + j;
                if (m >= M) continue;
                float v = acc[mi][ni][j];
                if (SCANEP) {
                    if (n < 512) {
                        v += bias[n];
                        v = fmaxf(v, 0.f) + log1pf(__expf(-fabsf(v)));
                        C[(size_t)m*ldc + n] = v;
                    } else {
                        bcbuf[(size_t)m*N_out + (n - 512)] = v;
                    }
                } else {
                    if (HAS_BIAS) v += bv;
                    if (RELU) v = fmaxf(v, 0.f);
                    if (WF32) C[(size_t)m*ldc + n] = v;
                    if (W3)   C3[(size_t)m*N_out + n] = f2bu(v);
                }
            }
        }
    }
}

// ---------------------------------------------------------------------------
// gemm4: 128x128 tile, 4 waves of 64x64 (acc 4x4), 64KB LDS double-buffered.
// For N divisible by 128. Same swizzle/fragment scheme as gemm3.
// ---------------------------------------------------------------------------
template<int HAS_BIAS, int RELU, int WF32, int W3>
__global__ __launch_bounds__(256)
void gemm4(const ushort* __restrict__ A3, int lda3,
           const ushort* __restrict__ W3p, int ldw3,
           const float* __restrict__ bias,
           float* __restrict__ C, int ldc,
           ushort* __restrict__ C3, int N_out,
           size_t aOff, size_t wOff, size_t biasOff, size_t cOff,
           int M, int Nn, int K3)
{
    const int dir = blockIdx.y;
    A3  += (size_t)dir * aOff;
    W3p += (size_t)dir * wOff;
    if (HAS_BIAS) bias += (size_t)dir * biasOff;
    if (WF32) C += (size_t)dir * cOff;

    __shared__ ushort lds[2][16384];   // [buf][A(128x64) | W(128x64)] : 64 KB
    const int tid  = threadIdx.x;
    const int lane = tid & 63;
    const int wid  = tid >> 6;
    const int wr = wid >> 1, wc = wid & 1;

    int nwg = gridDim.x;
    int q8 = nwg >> 3, r8 = nwg & 7;
    int xcd = blockIdx.x & 7;
    int idx = blockIdx.x >> 3;
    int swz = (xcd < r8 ? xcd*(q8+1) : r8*(q8+1) + (xcd-r8)*q8) + idx;
    int ntile = Nn >> 7;
    const int m0 = (swz / ntile) * 128;
    const int n0 = (swz % ntile) * 128;

    const int l8 = lane >> 3;
    const int sl = lane & 7;
    const int ssl = sl ^ l8;

    int arow[4], wrow[4];
    #pragma unroll
    for (int qq = 0; qq < 4; ++qq) {
        int r = (wid*4 + qq)*8 + l8;
        int ar = m0 + r; if (ar > M-1) ar = M-1;
        arow[qq] = ar;
        int wrr = n0 + r; if (wrr > Nn-1) wrr = Nn-1;
        wrow[qq] = wrr;
    }

    f32x4 acc[4][4];
    #pragma unroll
    for (int i = 0; i < 4; ++i)
        #pragma unroll
        for (int j = 0; j < 4; ++j) acc[i][j] = (f32x4){0.f,0.f,0.f,0.f};

    const int nk = K3 >> 6;
    const int rl = lane & 15;
    const int kq = lane >> 4;

    auto stage = [&](int buf_, int kt_) {
        #pragma unroll
        for (int qq = 0; qq < 4; ++qq) {
            int c = wid*4 + qq;
            gload_lds16(A3 + (size_t)arow[qq]*lda3 + kt_*64 + ssl*8,
                        (void*)&lds[buf_][c*512]);
            gload_lds16(W3p + (size_t)wrow[qq]*ldw3 + kt_*64 + ssl*8,
                        (void*)&lds[buf_][8192 + c*512]);
        }
    };

    stage(0, 0);
    __syncthreads();

    for (int kt = 0; kt < nk; ++kt) {
        int cur = kt & 1;
        if (kt + 1 < nk) stage(cur ^ 1, kt + 1);
        #pragma unroll
        for (int kk = 0; kk < 2; ++kk) {
            s16x8 av[4], wv[4];
            #pragma unroll
            for (int mi = 0; mi < 4; ++mi) {
                int row = wr*64 + mi*16 + rl;
                int ck = (kk*4 + kq) ^ (row & 7);
                av[mi] = *(const s16x8*)&lds[cur][row*64 + (ck<<3)];
            }
            #pragma unroll
            for (int ni = 0; ni < 4; ++ni) {
                int row = wc*64 + ni*16 + rl;
                int ck = (kk*4 + kq) ^ (row & 7);
                wv[ni] = *(const s16x8*)&lds[cur][8192 + row*64 + (ck<<3)];
            }
            #pragma unroll
            for (int mi = 0; mi < 4; ++mi)
                #pragma unroll
                for (int ni = 0; ni < 4; ++ni)
                    acc[mi][ni] = __builtin_amdgcn_mfma_f32_16x16x32_bf16(
                        av[mi], wv[ni], acc[mi][ni], 0, 0, 0);
        }
        __syncthreads();
    }

    #pragma unroll
    for (int ni = 0; ni < 4; ++ni) {
        int n = n0 + wc*64 + ni*16 + rl;
        float bv = HAS_BIAS ? bias[n] : 0.f;
        #pragma unroll
        for (int mi = 0; mi < 4; ++mi) {
            #pragma unroll
            for (int j = 0; j < 4; ++j) {
                int m = m0 + wr*64 + mi*16 + kq*4 + j;
                if (m >= M) continue;
                float v = acc[mi][ni][j];
                if (HAS_BIAS) v += bv;
                if (RELU) v = fmaxf(v, 0.f);
                if (WF32) C[(size_t)m*ldc + n] = v;
                if (W3)   C3[(size_t)m*N_out + n] = f2bu(v);
            }
        }
    }
}

// ---------------------------------------------------------------------------
// conv2: both dirs in one launch. xzb bf16 [M][2048]; writes merged xc fp32
// [M][1024], xcb bf16 [M][1024]; silu(z) in place (bf16).
// ---------------------------------------------------------------------------
__global__ __launch_bounds__(256)
void conv2(ushort* __restrict__ xzb, const float* __restrict__ cwB,
           const float* __restrict__ cbB, float* __restrict__ xc,
           ushort* __restrict__ xcb)
{
    int gid = blockIdx.x * 256 + threadIdx.x;   // 2*M*512 exact
    int d = gid & 511;
    int r = gid >> 9;
    int dir = (r >= MROWS) ? 1 : 0;
    int bt = r - dir*MROWS;
    int t = bt % TT;
    const float* cw = cwB + dir*DD*2;
    const float* cb = cbB + dir*DD;
    size_t base = (size_t)bt*2048 + (size_t)dir*1024;
    float cur = bu2f(xzb[base + d]);
    int tn = dir ? t + 1 : t - 1;
    float prev = 0.f;
    if (tn >= 0 && tn < TT)
        prev = bu2f(xzb[base + (dir ? 2048 : -2048) + d]);
    float v = prev*cw[d*2] + cur*cw[d*2+1] + cb[d];
    float sv = v / (1.f + __expf(-v));
    size_t o = (size_t)bt*1024 + dir*512 + d;
    xc[o] = sv;
    xcb[o] = f2bu(sv);
    float z = bu2f(xzb[base + 512 + d]);
    xzb[base + 512 + d] = f2bu(z / (1.f + __expf(-z)));
}

// ---------------------------------------------------------------------------
// Chunked scan pass 1, 16 states/thread (one d per lane, no cross-lane).
// grid (256 = 32b x 8dblk, NCHK-1, 2=dir), block 64. B/C rows wave-uniform.
// ---------------------------------------------------------------------------
__global__ __launch_bounds__(64)
void scan_p1(const float* __restrict__ sp_g, const float* __restrict__ xc_g,
             const float* __restrict__ bc_g, const float* __restrict__ alog,
             float* __restrict__ hs, float* __restrict__ ps)
{
    int dir = blockIdx.z;
    int rev = dir;
    sp_g += dir*512; xc_g += dir*512; bc_g += dir*32;
    alog += (size_t)dir*DD*SS;
    size_t doff = (size_t)dir*(NCHK-1)*65536*4;   // floats
    hs += doff; ps += doff;

    int sblk = blockIdx.x;
    int c    = blockIdx.y;
    int b  = sblk >> 3;
    int d  = ((sblk & 7) << 6) + threadIdx.x;

    float Ac[16];
    #pragma unroll
    for (int j = 0; j < 16; ++j)
        Ac[j] = -__expf(alog[d*SS + j]);

    float h[16], pp[16];
    #pragma unroll
    for (int j = 0; j < 16; ++j) { h[j] = 0.f; pp[j] = 1.f; }

    size_t bbase = (size_t)b*TT;
    int t0 = c*CSZ;
    for (int i = 0; i < CSZ; ++i) {
        int t = t0 + i;
        size_t p = bbase + (rev ? TT-1-t : t);
        float spv = sp_g[p*1024 + d];
        float xcv = xc_g[p*1024 + d];
        const float* bc = bc_g + p*64;
        float dtxc = spv*xcv;
        f32x4 Bq[4];
        #pragma unroll
        for (int q = 0; q < 4; ++q) Bq[q] = ((const f32x4*)bc)[q];
        #pragma unroll
        for (int j = 0; j < 16; ++j) {
            float e = __expf(spv*Ac[j]);
            h[j] = fmaf(e, h[j], dtxc*Bq[j>>2][j&3]);
            pp[j] *= e;
        }
    }
    size_t o = (((size_t)c*256 + sblk)*64 + threadIdx.x)*4;   // f4 units
    #pragma unroll
    for (int q = 0; q < 4; ++q) {
        ((f32x4*)hs)[o + q] = (f32x4){h[q*4+0], h[q*4+1], h[q*4+2], h[q*4+3]};
        ((f32x4*)ps)[o + q] = (f32x4){pp[q*4+0], pp[q*4+1], pp[q*4+2], pp[q*4+3]};
    }
}

// ---------------------------------------------------------------------------
// Chunked scan, combine (elementwise over the per-chunk blocks). grid (256,2).
// ---------------------------------------------------------------------------
__global__ __launch_bounds__(256)
void scan_comb(const float* __restrict__ hs, const float* __restrict__ ps,
               float* __restrict__ hin)
{
    int dir = blockIdx.y;
    size_t doff = (size_t)dir*(NCHK-1)*65536;   // in f4 units
    size_t gid = (size_t)blockIdx.x*256 + threadIdx.x;   // 65536
    float4 h = {0.f,0.f,0.f,0.f};
    for (int c = 0; c < NCHK-1; ++c) {
        size_t o = doff + (size_t)c*65536 + gid;
        float4 hl = ((const float4*)hs)[o];
        float4 pv = ((const float4*)ps)[o];
        h.x = fmaf(pv.x, h.x, hl.x);
        h.y = fmaf(pv.y, h.y, hl.y);
        h.z = fmaf(pv.z, h.z, hl.z);
        h.w = fmaf(pv.w, h.w, hl.w);
        ((float4*)hin)[o] = h;
    }
}

// ---------------------------------------------------------------------------
// Chunked scan pass 2, 16 states/thread. grid (256, NCHK, 2), block 64.
// ---------------------------------------------------------------------------
__global__ __launch_bounds__(64)
void scan_p2(const float* __restrict__ sp_g, const float* __restrict__ xc_g,
             const ushort* __restrict__ xz_u, const float* __restrict__ bc_g,
             const float* __restrict__ alog, const float* __restrict__ dparam,
             const float* __restrict__ hin, ushort* __restrict__ yb)
{
    int dir = blockIdx.z;
    int rev = dir;
    sp_g += dir*512; xc_g += dir*512; bc_g += dir*32; xz_u += dir*1024;
    alog += (size_t)dir*DD*SS; dparam += (size_t)dir*DD;
    hin += (size_t)dir*(NCHK-1)*65536*4;
    yb  += (size_t)dir*(size_t)MROWS*512;

    int sblk = blockIdx.x;
    int c    = blockIdx.y;
    int b  = sblk >> 3;
    int d  = ((sblk & 7) << 6) + threadIdx.x;

    float Ac[16];
    #pragma unroll
    for (int j = 0; j < 16; ++j)
        Ac[j] = -__expf(alog[d*SS + j]);
    float dp = dparam[d];

    float h[16];
    #pragma unroll
    for (int j = 0; j < 16; ++j) h[j] = 0.f;
    if (c > 0) {
        size_t o = (((size_t)(c-1)*256 + sblk)*64 + threadIdx.x)*4;
        #pragma unroll
        for (int q = 0; q < 4; ++q) {
            f32x4 hv = ((const f32x4*)hin)[o + q];
            h[q*4+0]=hv[0]; h[q*4+1]=hv[1]; h[q*4+2]=hv[2]; h[q*4+3]=hv[3];
        }
    }

    size_t bbase = (size_t)b*TT;
    int t0 = c*CSZ;
    for (int i = 0; i < CSZ; ++i) {
        int t = t0 + i;
        int tc = t < TT ? t : TT-1;
        size_t p = bbase + (rev ? TT-1-tc : tc);
        float spv = sp_g[p*1024 + d];
        float xcv = xc_g[p*1024 + d];
        float zsv = bu2f(xz_u[p*2048 + 512 + d]);
        const float* bc = bc_g + p*64;
        float dtxc = spv*xcv;
        f32x4 Bq[4], Cq[4];
        #pragma unroll
        for (int q = 0; q < 4; ++q) {
            Bq[q] = ((const f32x4*)bc)[q];
            Cq[q] = ((const f32x4*)(bc + 16))[q];
        }
        #pragma unroll
        for (int j = 0; j < 16; ++j) {
            float e = __expf(spv*Ac[j]);
            h[j] = fmaf(e, h[j], dtxc*Bq[j>>2][j&3]);
        }
        float p0 = 0.f, p1 = 0.f, p2 = 0.f, p3 = 0.f;
        #pragma unroll
        for (int q = 0; q < 4; ++q) {
            p0 = fmaf(h[q*4+0], Cq[q][0], p0);
            p1 = fmaf(h[q*4+1], Cq[q][1], p1);
            p2 = fmaf(h[q*4+2], Cq[q][2], p2);
            p3 = fmaf(h[q*4+3], Cq[q][3], p3);
        }
        float dot = (p0 + p1) + (p2 + p3);
        if (t < TT) {
            int tg = rev ? TT-1-t : t;
            float yv = (dot + dp*xcv) * zsv;
            yb[(bbase + tg)*512 + d] = f2bu(yv);
        }
    }
}

// ---------------------------------------------------------------------------
// LayerNorm (up to 3 summed inputs), optional bf16 output
// ---------------------------------------------------------------------------
__global__ __launch_bounds__(64)
void ln_kernel(float* __restrict__ dst, const float* __restrict__ a,
               const float* __restrict__ b, const float* __restrict__ c,
               const float* __restrict__ g, const float* __restrict__ beta,
               ushort* __restrict__ outb)
{
    int row = blockIdx.x;
    int lane = threadIdx.x;
    size_t base = (size_t)row * DD;
    float x[8];
    #pragma unroll
    for (int j = 0; j < 2; ++j) {
        int e4 = j*64 + lane;
        float4 v = *(const float4*)(a + base + (size_t)e4*4);
        if (b) { float4 t = *(const float4*)(b + base + (size_t)e4*4); v.x+=t.x; v.y+=t.y; v.z+=t.z; v.w+=t.w; }
        if (c) { float4 t = *(const float4*)(c + base + (size_t)e4*4); v.x+=t.x; v.y+=t.y; v.z+=t.z; v.w+=t.w; }
        x[j*4+0]=v.x; x[j*4+1]=v.y; x[j*4+2]=v.z; x[j*4+3]=v.w;
    }
    float s = 0.f;
    #pragma unroll
    for (int i = 0; i < 8; ++i) s += x[i];
    #pragma unroll
    for (int m = 1; m < 64; m <<= 1) s += __shfl_xor(s, m);
    float mu = s * (1.f/DD);
    float vs = 0.f;
    #pragma unroll
    for (int i = 0; i < 8; ++i) { float dd = x[i]-mu; vs += dd*dd; }
    #pragma unroll
    for (int m = 1; m < 64; m <<= 1) vs += __shfl_xor(vs, m);
    float r = rsqrtf(vs*(1.f/DD) + 1e-5f);
    #pragma unroll
    for (int j = 0; j < 2; ++j) {
        int e4 = j*64 + lane;
        float4 gv = *(const float4*)(g    + (size_t)e4*4);
        float4 bv = *(const float4*)(beta + (size_t)e4*4);
        float4 o;
        o.x = (x[j*4+0]-mu)*r*gv.x + bv.x;
        o.y = (x[j*4+1]-mu)*r*gv.y + bv.y;
        o.z = (x[j*4+2]-mu)*r*gv.z + bv.z;
        o.w = (x[j*4+3]-mu)*r*gv.w + bv.w;
        *(float4*)(dst + base + (size_t)e4*4) = o;
        if (outb) {
            ushort* ob = outb + (size_t)row*512;
            ob[e4*4+0] = f2bu(o.x);
            ob[e4*4+1] = f2bu(o.y);
            ob[e4*4+2] = f2bu(o.z);
            ob[e4*4+3] = f2bu(o.w);
        }
    }
}

// ---------------------------------------------------------------------------
// proj finish: transpose [b*TT+n][96] -> out[b][p][n], de-normalize.
// ---------------------------------------------------------------------------
__global__ __launch_bounds__(256)
void proj_fin(const float* __restrict__ projtmp, const float* __restrict__ mean,
              const float* __restrict__ stdv, float* __restrict__ out)
{
    int b  = blockIdx.x >> 2;
    int n0 = (blockIdx.x & 3) << 6;
    __shared__ float tile[64][97];
    for (int i = threadIdx.x; i < 64*96; i += 256) {
        int rj = i / 96, cp = i % 96;
        tile[rj][cp] = projtmp[((size_t)b*TT + n0 + rj)*96 + cp];
    }
    __syncthreads();
    int nl = threadIdx.x & 63;
    int pg = threadIdx.x >> 6;          // 0..3
    int n = n0 + nl;
    float sd = stdv[b*NV + n];
    float mu = mean[b*NV + n];
    #pragma unroll
    for (int i = 0; i < 24; ++i) {
        int p = pg*24 + i;
        out[((size_t)b*PRED + p)*NV + n] = tile[nl][p]*sd + mu;
    }
}

// ---------------------------------------------------------------------------
extern "C" void kernel_launch(void* const* d_in, const int* in_sizes, int n_in,
                              void* d_out, int out_size, void* d_ws, size_t ws_size,
                              hipStream_t stream)
{
    (void)in_sizes; (void)n_in; (void)out_size; (void)ws_size;
    const float* x_enc   = (const float*)d_in[0];
    const float* x_mark  = (const float*)d_in[1];
    const float* emb_w   = (const float*)d_in[2];
    const float* emb_b   = (const float*)d_in[3];
    const float* m_win   = (const float*)d_in[4];
    const float* m_convw = (const float*)d_in[5];
    const float* m_convb = (const float*)d_in[6];
    const float* m_wx    = (const float*)d_in[7];
    const float* m_wdt   = (const float*)d_in[8];
    const float* m_bdt   = (const float*)d_in[9];
    const float* m_alog  = (const float*)d_in[10];
    const float* m_dpar  = (const float*)d_in[11];
    const float* m_wout  = (const float*)d_in[12];
    const float* ln1_g   = (const float*)d_in[13];
    const float* ln1_b   = (const float*)d_in[14];
    const float* ff1_w   = (const float*)d_in[15];
    const float* ff1_b   = (const float*)d_in[16];
    const float* ff2_w   = (const float*)d_in[17];
    const float* ff2_b   = (const float*)d_in[18];
    const float* ln2_g   = (const float*)d_in[19];
    const float* ln2_b   = (const float*)d_in[20];
    const float* lnf_g   = (const float*)d_in[21];
    const float* lnf_b   = (const float*)d_in[22];
    const float* proj_w  = (const float*)d_in[23];
    const float* proj_b  = (const float*)d_in[24];
    float* out = (float*)d_out;

    float* ws = (float*)d_ws;
    const size_t NBT = (size_t)MROWS;
    size_t off = 0;
    float* mean = ws + off; off += 8192;
    float* stdv = ws + off; off += 8192;
    ushort* w_emb  = (ushort*)(ws + off); off += 131072;     // 512*512 ush
    ushort* w_win  = (ushort*)(ws + off); off += 1048576;    // 4096*512 ush
    ushort* w_wout = (ushort*)(ws + off); off += 524288;     // 2048*512 ush
    ushort* w_ff1  = (ushort*)(ws + off); off += 262144;     // 1024*512 ush
    ushort* w_ff2  = (ushort*)(ws + off); off += 262144;
    ushort* w_comb = (ushort*)(ws + off); off += 557056;     // 4*544*512 ush
    ushort* w_proj = (ushort*)(ws + off); off += 24576;      // 96*512 ush
    ushort* pool = (ushort*)(ws + off); off += NBT*768;      // tokb | xcb | yb2
    ushort* tokb = pool;                                     // [M][512] ush
    ushort* xcb  = pool;                                     // [M][1024] ush
    ushort* yb   = pool;                                     // [2M][512] ush (row-stacked)
    float* h   = ws + off; off += NBT*512;
    ushort* hb = (ushort*)(ws + off); off += NBT*256;        // [M][512] ush
    ushort* xzb = (ushort*)(ws + off); off += NBT*1024;      // [M][2048] ush
    ushort* fftb = xzb;                                      // alias (xzb dead at ffn)
    float* xc  = ws + off; off += NBT*1024;                  // merged [M][1024]
    float* bc2 = ws + off; off += NBT*64;                    // merged [M][64]
    float* sp  = ws + off; off += NBT*1024;                  // merged [M][1024]
    float* fbuf = ws + off; off += NBT*512;                  // fbuf|rbuf contiguous
    float* rbuf = ws + off; off += NBT*512;
    float* hs  = ws + off; off += (size_t)2*(NCHK-1)*65536*4;
    float* psb = ws + off; off += (size_t)2*(NCHK-1)*65536*4;
    float* hin = ws + off; off += (size_t)2*(NCHK-1)*65536*4;
    float* projtmp = ws + off; off += NBT*96;
    (void)rbuf;

    // ---- weight packing: ONE launch for all 6 bf16 casts ----
    packall<<<dim3((4505600+255)/256), 256, 0, stream>>>(
        emb_w, w_emb, m_win, w_win, m_wout, w_wout,
        ff1_w, w_ff1, ff2_w, w_ff2, proj_w, w_proj);
    mkcomb<<<dim3(544,4), 256, 0, stream>>>(m_wx, m_wdt, w_comb);

    stats_kernel<<<dim3(BB*16), 256, 0, stream>>>(x_enc, mean, stdv);
    tok_kernel<<<dim3(BB*40), 256, 0, stream>>>(x_enc, x_mark, mean, stdv, tokb);

    gemm4<1,0,1,1><<<dim3(66*4), 256, 0, stream>>>(tokb, 512, w_emb, 512,
        emb_b, h, DD, hb, 512, 0,0,0,0, MROWS, 512, 512);

    for (int l = 0; l < 2; ++l) {
        // merged win: N=2048 (both dirs), bf16 out
        gemm4<0,0,0,1><<<dim3(66*16), 256, 0, stream>>>(hb, 512,
            w_win + (size_t)l*2048*512, 512, nullptr,
            nullptr, 0, xzb, 2048, 0,0,0,0, MROWS, 2048, 512);
        conv2<<<dim3((2*MROWS*DD)/256), 256, 0, stream>>>(xzb,
            m_convw + (size_t)l*2*DD*2, m_convb + (size_t)l*2*DD, xc, xcb);
        // comb GEMM (N=544), both dirs batched via gridDim.y -- gemm3
        gemm3<0,0,0,0,1><<<dim3(66*9, 2), 256, 0, stream>>>(
            xcb, 1024, w_comb + (size_t)l*2*544*512, 512,
            m_bdt + (size_t)l*2*DD, sp, 1024, nullptr, 64, bc2,
            /*aOff*/512, /*wOff*/(size_t)544*512, /*biasOff*/512,
            /*cOff*/512, /*bcOff*/32, MROWS, 544, 512);
        // scans, 16-state chunked, both dirs batched via grid.z / grid.y
        const float* al = m_alog + (size_t)l*2*DD*SS;
        const float* dpp = m_dpar + (size_t)l*2*DD;
        scan_p1<<<dim3(256, NCHK-1, 2), 64, 0, stream>>>(sp, xc, bc2, al,
            hs, psb);
        scan_comb<<<dim3(256, 2), 256, 0, stream>>>(hs, psb, hin);
        scan_p2<<<dim3(256, NCHK, 2), 64, 0, stream>>>(sp, xc, xzb, bc2,
            al, dpp, hin, yb);
        // wout, both dirs batched: A rows stacked, C fbuf|rbuf contiguous
        gemm4<0,0,1,0><<<dim3(66*4, 2), 256, 0, stream>>>(yb, 512,
            w_wout + (size_t)l*2*512*512, 512, nullptr,
            fbuf, DD, nullptr, 0,
            /*aOff*/NBT*512, /*wOff*/(size_t)512*512, /*biasOff*/0,
            /*cOff*/NBT*512, MROWS, 512, 512);
        ln_kernel<<<dim3(MROWS), 64, 0, stream>>>(h, h, fbuf, rbuf,
            ln1_g + l*DD, ln1_b + l*DD, hb);
        gemm4<1,1,0,1><<<dim3(66*4), 256, 0, stream>>>(hb, 512,
            w_ff1 + (size_t)l*512*512, 512, ff1_b + l*DD,
            nullptr, 0, fftb, 512, 0,0,0,0, MROWS, 512, 512);
        gemm4<1,0,1,0><<<dim3(66*4), 256, 0, stream>>>(fftb, 512,
            w_ff2 + (size_t)l*512*512, 512, ff2_b + l*DD,
            xc, DD, nullptr, 0, 0,0,0,0, MROWS, 512, 512);
        ln_kernel<<<dim3(MROWS), 64, 0, stream>>>(h, h, xc, nullptr,
            ln2_g + l*DD, ln2_b + l*DD, hb);
    }
    ln_kernel<<<dim3(MROWS), 64, 0, stream>>>(fbuf, h, nullptr, nullptr,
                                              lnf_g, lnf_b, hb);
    gemm3<1,0,1,0,0><<<dim3(66*2), 256, 0, stream>>>(hb, 512, w_proj, 512,
        proj_b, projtmp, 96, nullptr, 0, nullptr, 0,0,0,0,0, MROWS, 96, 512);
    proj_fin<<<dim3(BB*4), 256, 0, stream>>>(projtmp, mean, stdv, out);
}

// Round 36
// 623.891 us; speedup vs baseline: 1.0624x; 1.0624x over previous
//
#include <hip/hip_runtime.h>
#include <hip/hip_bf16.h>
#include <math.h>
#include <stddef.h>

#define BB 32
#define TT 262
#define DD 512
#define SS 16
#define RR 32
#define SEQ 512
#define NV 256
#define PRED 96
#define MROWS (BB*TT)   // 8384
#define NCHK 8
#define CSZ 33          // 8*33 = 264 >= 262

typedef __attribute__((ext_vector_type(4))) float f32x4;
typedef __attribute__((ext_vector_type(8))) short s16x8;

// ---------------- bf16 helpers ----------------
__device__ inline ushort f2bu(float x) {
    __hip_bfloat16 h = __float2bfloat16(x);
    ushort u; __builtin_memcpy(&u, &h, 2); return u;
}
__device__ inline float bu2f(ushort u) {
    __hip_bfloat16 h; __builtin_memcpy(&h, &u, 2);
    return __bfloat162float(h);
}

// async global->LDS, 16B per lane
__device__ inline void gload_lds16(const void* g, void* l) {
    __builtin_amdgcn_global_load_lds(
        (const __attribute__((address_space(1))) void*)g,
        (__attribute__((address_space(3))) void*)l, 16, 0, 0);
}

// ---------------------------------------------------------------------------
// merged weight bf16 cast: all 6 weights in ONE launch.
// ---------------------------------------------------------------------------
__global__ __launch_bounds__(256)
void packall(const float* __restrict__ s0, ushort* __restrict__ d0,  // emb 262144
             const float* __restrict__ s1, ushort* __restrict__ d1,  // win 2097152
             const float* __restrict__ s2, ushort* __restrict__ d2,  // wout 1048576
             const float* __restrict__ s3, ushort* __restrict__ d3,  // ff1 524288
             const float* __restrict__ s4, ushort* __restrict__ d4,  // ff2 524288
             const float* __restrict__ s5, ushort* __restrict__ d5)  // proj 49152
{
    int idx = blockIdx.x * 256 + threadIdx.x;
    const float* s; ushort* dst; int o;
    if      (idx < 262144)  { s = s0; dst = d0; o = idx; }
    else if (idx < 2359296) { s = s1; dst = d1; o = idx - 262144; }
    else if (idx < 3407872) { s = s2; dst = d2; o = idx - 2359296; }
    else if (idx < 3932160) { s = s3; dst = d3; o = idx - 3407872; }
    else if (idx < 4456448) { s = s4; dst = d4; o = idx - 3932160; }
    else if (idx < 4505600) { s = s5; dst = d5; o = idx - 4456448; }
    else return;
    dst[o] = f2bu(s[o]);
}

// ---------------------------------------------------------------------------
// combined scan-projection weight (dt path folded through wdt), bf16
// ---------------------------------------------------------------------------
__global__ __launch_bounds__(256)
void mkcomb(const float* __restrict__ wx, const float* __restrict__ wdt,
            ushort* __restrict__ comb)
{
    int n  = blockIdx.x;
    int li = blockIdx.y;
    const float* wxl = wx + (size_t)li*64*512;
    ushort* outb = comb + ((size_t)li*544 + n)*512;
    if (n < 512) {
        __shared__ float wr[32];
        if (threadIdx.x < 32)
            wr[threadIdx.x] = wdt[(size_t)li*512*32 + (size_t)n*32 + threadIdx.x];
        __syncthreads();
        for (int kk = threadIdx.x; kk < 512; kk += 256) {
            float acc = 0.f;
            #pragma unroll
            for (int r = 0; r < 32; ++r)
                acc = fmaf(wr[r], wxl[r*512 + kk], acc);
            outb[kk] = f2bu(acc);
        }
    } else {
        int s = n - 512;
        for (int kk = threadIdx.x; kk < 512; kk += 256)
            outb[kk] = f2bu(wxl[(32+s)*512 + kk]);
    }
}

// ---------------------------------------------------------------------------
// per-(b,n) mean/std over SEQ. grid = BB*16, block 256 = 16n x 16tg.
// ---------------------------------------------------------------------------
__global__ __launch_bounds__(256)
void stats_kernel(const float* __restrict__ x_enc,
                  float* __restrict__ mean, float* __restrict__ stdv)
{
    int b  = blockIdx.x >> 4;
    int n0 = (blockIdx.x & 15) << 4;
    int nl = threadIdx.x & 15;
    int tg = threadIdx.x >> 4;
    int n = n0 + nl;
    const float* base = x_enc + (size_t)b*SEQ*NV + n;
    float s0 = 0.f, s1 = 0.f, q0 = 0.f, q1 = 0.f;
    #pragma unroll 8
    for (int i = 0; i < 16; ++i) {
        int t = tg + i*32;
        float v0 = base[(size_t)t*NV];
        float v1 = base[(size_t)(t+16)*NV];
        s0 += v0; q0 = fmaf(v0, v0, q0);
        s1 += v1; q1 = fmaf(v1, v1, q1);
    }
    float s = s0 + s1, q = q0 + q1;
    __shared__ float ls[16][17], lq[16][17];
    ls[tg][nl] = s; lq[tg][nl] = q;
    __syncthreads();
    if (tg < 8) { ls[tg][nl] += ls[tg+8][nl]; lq[tg][nl] += lq[tg+8][nl]; }
    __syncthreads();
    if (tg < 4) { ls[tg][nl] += ls[tg+4][nl]; lq[tg][nl] += lq[tg+4][nl]; }
    __syncthreads();
    if (tg < 2) { ls[tg][nl] += ls[tg+2][nl]; lq[tg][nl] += lq[tg+2][nl]; }
    __syncthreads();
    if (tg == 0) {
        s = ls[0][nl] + ls[1][nl];
        q = lq[0][nl] + lq[1][nl];
        float mu  = s * (1.f/SEQ);
        float var = q * (1.f/SEQ) - mu*mu;
        mean[b*NV + n] = mu;
        stdv[b*NV + n] = sqrtf(var + 1e-5f);
    }
}

// ---------------------------------------------------------------------------
// tok: normalized transpose, bf16 rows of 512
// ---------------------------------------------------------------------------
__global__ __launch_bounds__(256)
void tok_kernel(const float* __restrict__ x_enc, const float* __restrict__ x_mark,
                const float* __restrict__ mean, const float* __restrict__ stdv,
                ushort* __restrict__ tokb)
{
    int b  = blockIdx.x / 40;
    int r  = blockIdx.x % 40;
    int tt = r / 5;
    int vt = r % 5;
    int t0 = tt << 6, v0 = vt << 6;
    __shared__ float tile[64][65];
    int lv = threadIdx.x & 63;
    for (int i = threadIdx.x >> 6; i < 64; i += 4) {
        int t = t0 + i, v = v0 + lv;
        float val = 0.f;
        if (v < NV) {
            val = (x_enc[((size_t)b*SEQ + t)*NV + v] - mean[b*NV + v]) / stdv[b*NV + v];
        } else if (v < TT) {
            val = x_mark[((size_t)b*SEQ + t)*6 + (v - NV)];
        }
        tile[i][lv] = val;
    }
    __syncthreads();
    for (int i = threadIdx.x >> 6; i < 64; i += 4) {
        int v = v0 + i;
        if (v < TT) {
            size_t row = (size_t)b*TT + v;
            tokb[row*512 + t0 + lv] = f2bu(tile[lv][i]);
        }
    }
}

// ---------------------------------------------------------------------------
// bf16 MFMA GEMM (NT; K multiple of 64). 128x64 tile, 4 waves (2M x 2N of
// 64x32), double-buffered 48KB LDS. grid = (66 * ntile(Nn), NDIR).
// SCANEP: n<512 -> softplus -> bf16 C3[m*ldc+n]; n>=512 -> bcbuf fp32.
// ---------------------------------------------------------------------------
template<int HAS_BIAS, int RELU, int WF32, int W3, int SCANEP>
__global__ __launch_bounds__(256)
void gemm3(const ushort* __restrict__ A3, int lda3,
           const ushort* __restrict__ W3p, int ldw3,
           const float* __restrict__ bias,
           float* __restrict__ C, int ldc,
           ushort* __restrict__ C3, int N_out,
           float* __restrict__ bcbuf,
           size_t aOff, size_t wOff, size_t biasOff, size_t cOff, size_t bcOff,
           int M, int Nn, int K3)
{
    const int dir = blockIdx.y;
    A3  += (size_t)dir * aOff;
    W3p += (size_t)dir * wOff;
    if (HAS_BIAS || SCANEP) bias += (size_t)dir * biasOff;
    if (WF32) C += (size_t)dir * cOff;
    if (W3 || SCANEP) C3 += (size_t)dir * cOff;
    if (SCANEP) bcbuf += (size_t)dir * bcOff;

    __shared__ ushort lds[2][192*64];   // [buf][A(128x64) | W(64x64)] : 48 KB
    const int tid  = threadIdx.x;
    const int lane = tid & 63;
    const int wid  = tid >> 6;
    const int wr = wid >> 1, wc = wid & 1;

    int nwg = gridDim.x;
    int q8 = nwg >> 3, r8 = nwg & 7;
    int xcd = blockIdx.x & 7;
    int idx = blockIdx.x >> 3;
    int swz = (xcd < r8 ? xcd*(q8+1) : r8*(q8+1) + (xcd-r8)*q8) + idx;
    int ntile = (Nn + 63) >> 6;
    const int m0 = (swz / ntile) * 128;
    const int n0 = (swz % ntile) * 64;

    const int l8 = lane >> 3;
    const int sl = lane & 7;
    const int ssl = sl ^ l8;

    int arow[4], wrow[2];
    #pragma unroll
    for (int qq = 0; qq < 4; ++qq) {
        int r = (wid*4 + qq)*8 + l8;
        int ar = m0 + r; if (ar > M-1) ar = M-1;
        arow[qq] = ar;
    }
    #pragma unroll
    for (int qq = 0; qq < 2; ++qq) {
        int r = (wid*2 + qq)*8 + l8;
        int wrr = n0 + r; if (wrr > Nn-1) wrr = Nn-1;
        wrow[qq] = wrr;
    }

    f32x4 acc[4][2];
    #pragma unroll
    for (int i = 0; i < 4; ++i)
        #pragma unroll
        for (int j = 0; j < 2; ++j) acc[i][j] = (f32x4){0.f,0.f,0.f,0.f};

    const int nk = K3 >> 6;
    const int rl = lane & 15;
    const int kq = lane >> 4;

    auto stage = [&](int buf_, int kt_) {
        #pragma unroll
        for (int qq = 0; qq < 4; ++qq) {
            int c = wid*4 + qq;
            gload_lds16(A3 + (size_t)arow[qq]*lda3 + kt_*64 + ssl*8,
                        (void*)&lds[buf_][c*512]);
        }
        #pragma unroll
        for (int qq = 0; qq < 2; ++qq) {
            int c = wid*2 + qq;
            gload_lds16(W3p + (size_t)wrow[qq]*ldw3 + kt_*64 + ssl*8,
                        (void*)&lds[buf_][8192 + c*512]);
        }
    };

    stage(0, 0);
    __syncthreads();

    for (int kt = 0; kt < nk; ++kt) {
        int cur = kt & 1;
        if (kt + 1 < nk) stage(cur ^ 1, kt + 1);
        #pragma unroll
        for (int kk = 0; kk < 2; ++kk) {
            s16x8 av[4], wv[2];
            #pragma unroll
            for (int mi = 0; mi < 4; ++mi) {
                int row = wr*64 + mi*16 + rl;
                int ck = (kk*4 + kq) ^ (row & 7);
                av[mi] = *(const s16x8*)&lds[cur][row*64 + (ck<<3)];
            }
            #pragma unroll
            for (int ni = 0; ni < 2; ++ni) {
                int row = wc*32 + ni*16 + rl;
                int ck = (kk*4 + kq) ^ (row & 7);
                wv[ni] = *(const s16x8*)&lds[cur][8192 + row*64 + (ck<<3)];
            }
            #pragma unroll
            for (int mi = 0; mi < 4; ++mi)
                #pragma unroll
                for (int ni = 0; ni < 2; ++ni)
                    acc[mi][ni] = __builtin_amdgcn_mfma_f32_16x16x32_bf16(
                        av[mi], wv[ni], acc[mi][ni], 0, 0, 0);
        }
        __syncthreads();
    }

    #pragma unroll
    for (int ni = 0; ni < 2; ++ni) {
        int n = n0 + wc*32 + ni*16 + rl;
        if (n >= Nn) continue;
        float bv = (HAS_BIAS && !SCANEP) ? bias[n] : 0.f;
        #pragma unroll
        for (int mi = 0; mi < 4; ++mi) {
            #pragma unroll
            for (int j = 0; j < 4; ++j) {
                int m = m0 + wr*64 + mi*16 + kq*4 + j;
                if (m >= M) continue;
                float v = acc[mi][ni][j];
                if (SCANEP) {
                    if (n < 512) {
                        v += bias[n];
                        v = fmaxf(v, 0.f) + log1pf(__expf(-fabsf(v)));
                        C3[(size_t)m*ldc + n] = f2bu(v);
                    } else {
                        bcbuf[(size_t)m*N_out + (n - 512)] = v;
                    }
                } else {
                    if (HAS_BIAS) v += bv;
                    if (RELU) v = fmaxf(v, 0.f);
                    if (WF32) C[(size_t)m*ldc + n] = v;
                    if (W3)   C3[(size_t)m*N_out + n] = f2bu(v);
                }
            }
        }
    }
}

// ---------------------------------------------------------------------------
// conv2: both dirs in one launch. xzb bf16 [M][2048]; writes merged xc fp32
// [M][1024], xcb bf16 [M][1024]; silu(z) in place (bf16).
// ---------------------------------------------------------------------------
__global__ __launch_bounds__(256)
void conv2(ushort* __restrict__ xzb, const float* __restrict__ cwB,
           const float* __restrict__ cbB, float* __restrict__ xc,
           ushort* __restrict__ xcb)
{
    int gid = blockIdx.x * 256 + threadIdx.x;   // 2*M*512 exact
    int d = gid & 511;
    int r = gid >> 9;
    int dir = (r >= MROWS) ? 1 : 0;
    int bt = r - dir*MROWS;
    int t = bt % TT;
    const float* cw = cwB + dir*DD*2;
    const float* cb = cbB + dir*DD;
    size_t base = (size_t)bt*2048 + (size_t)dir*1024;
    float cur = bu2f(xzb[base + d]);
    int tn = dir ? t + 1 : t - 1;
    float prev = 0.f;
    if (tn >= 0 && tn < TT)
        prev = bu2f(xzb[base + (dir ? 2048 : -2048) + d]);
    float v = prev*cw[d*2] + cur*cw[d*2+1] + cb[d];
    float sv = v / (1.f + __expf(-v));
    size_t o = (size_t)bt*1024 + dir*512 + d;
    xc[o] = sv;
    xcb[o] = f2bu(sv);
    float z = bu2f(xzb[base + 512 + d]);
    xzb[base + 512 + d] = f2bu(z / (1.f + __expf(-z)));
}

// ---------------------------------------------------------------------------
// Chunked scan pass 1, 16 states/thread. sp bf16 / xc fp32.
// grid (256 = 32b x 8dblk, NCHK-1, 2=dir), block 64.
// ---------------------------------------------------------------------------
__global__ __launch_bounds__(64)
void scan_p1(const ushort* __restrict__ sp_g, const float* __restrict__ xc_g,
             const float* __restrict__ bc_g, const float* __restrict__ alog,
             float* __restrict__ hs, float* __restrict__ ps)
{
    int dir = blockIdx.z;
    int rev = dir;
    sp_g += dir*512; xc_g += dir*512; bc_g += dir*32;
    alog += (size_t)dir*DD*SS;
    size_t doff = (size_t)dir*(NCHK-1)*65536*4;   // floats
    hs += doff; ps += doff;

    int sblk = blockIdx.x;
    int c    = blockIdx.y;
    int b  = sblk >> 3;
    int d  = ((sblk & 7) << 6) + threadIdx.x;

    float Ac[16];
    #pragma unroll
    for (int j = 0; j < 16; ++j)
        Ac[j] = -__expf(alog[d*SS + j]);

    float h[16], pp[16];
    #pragma unroll
    for (int j = 0; j < 16; ++j) { h[j] = 0.f; pp[j] = 1.f; }

    size_t bbase = (size_t)b*TT;
    int t0 = c*CSZ;
    for (int i = 0; i < CSZ; ++i) {
        int t = t0 + i;
        size_t p = bbase + (rev ? TT-1-t : t);
        float spv = bu2f(sp_g[p*1024 + d]);
        float xcv = xc_g[p*1024 + d];
        const float* bc = bc_g + p*64;
        float dtxc = spv*xcv;
        f32x4 Bq[4];
        #pragma unroll
        for (int q = 0; q < 4; ++q) Bq[q] = ((const f32x4*)bc)[q];
        #pragma unroll
        for (int j = 0; j < 16; ++j) {
            float e = __expf(spv*Ac[j]);
            h[j] = fmaf(e, h[j], dtxc*Bq[j>>2][j&3]);
            pp[j] *= e;
        }
    }
    size_t o = (((size_t)c*256 + sblk)*64 + threadIdx.x)*4;   // f4 units
    #pragma unroll
    for (int q = 0; q < 4; ++q) {
        ((f32x4*)hs)[o + q] = (f32x4){h[q*4+0], h[q*4+1], h[q*4+2], h[q*4+3]};
        ((f32x4*)ps)[o + q] = (f32x4){pp[q*4+0], pp[q*4+1], pp[q*4+2], pp[q*4+3]};
    }
}

// ---------------------------------------------------------------------------
// Chunked scan, combine (elementwise over the per-chunk blocks). grid (256,2).
// ---------------------------------------------------------------------------
__global__ __launch_bounds__(256)
void scan_comb(const float* __restrict__ hs, const float* __restrict__ ps,
               float* __restrict__ hin)
{
    int dir = blockIdx.y;
    size_t doff = (size_t)dir*(NCHK-1)*65536;   // in f4 units
    size_t gid = (size_t)blockIdx.x*256 + threadIdx.x;   // 65536
    float4 h = {0.f,0.f,0.f,0.f};
    for (int c = 0; c < NCHK-1; ++c) {
        size_t o = doff + (size_t)c*65536 + gid;
        float4 hl = ((const float4*)hs)[o];
        float4 pv = ((const float4*)ps)[o];
        h.x = fmaf(pv.x, h.x, hl.x);
        h.y = fmaf(pv.y, h.y, hl.y);
        h.z = fmaf(pv.z, h.z, hl.z);
        h.w = fmaf(pv.w, h.w, hl.w);
        ((float4*)hin)[o] = h;
    }
}

// ---------------------------------------------------------------------------
// Chunked scan pass 2, 16 states/thread. sp bf16 / xc fp32 / z bf16.
// grid (256, NCHK, 2), block 64.
// ---------------------------------------------------------------------------
__global__ __launch_bounds__(64)
void scan_p2(const ushort* __restrict__ sp_g, const float* __restrict__ xc_g,
             const ushort* __restrict__ xz_u, const float* __restrict__ bc_g,
             const float* __restrict__ alog, const float* __restrict__ dparam,
             const float* __restrict__ hin, ushort* __restrict__ yb)
{
    int dir = blockIdx.z;
    int rev = dir;
    sp_g += dir*512; xc_g += dir*512; bc_g += dir*32; xz_u += dir*1024;
    alog += (size_t)dir*DD*SS; dparam += (size_t)dir*DD;
    hin += (size_t)dir*(NCHK-1)*65536*4;
    yb  += (size_t)dir*(size_t)MROWS*512;

    int sblk = blockIdx.x;
    int c    = blockIdx.y;
    int b  = sblk >> 3;
    int d  = ((sblk & 7) << 6) + threadIdx.x;

    float Ac[16];
    #pragma unroll
    for (int j = 0; j < 16; ++j)
        Ac[j] = -__expf(alog[d*SS + j]);
    float dp = dparam[d];

    float h[16];
    #pragma unroll
    for (int j = 0; j < 16; ++j) h[j] = 0.f;
    if (c > 0) {
        size_t o = (((size_t)(c-1)*256 + sblk)*64 + threadIdx.x)*4;
        #pragma unroll
        for (int q = 0; q < 4; ++q) {
            f32x4 hv = ((const f32x4*)hin)[o + q];
            h[q*4+0]=hv[0]; h[q*4+1]=hv[1]; h[q*4+2]=hv[2]; h[q*4+3]=hv[3];
        }
    }

    size_t bbase = (size_t)b*TT;
    int t0 = c*CSZ;
    for (int i = 0; i < CSZ; ++i) {
        int t = t0 + i;
        int tc = t < TT ? t : TT-1;
        size_t p = bbase + (rev ? TT-1-tc : tc);
        float spv = bu2f(sp_g[p*1024 + d]);
        float xcv = xc_g[p*1024 + d];
        float zsv = bu2f(xz_u[p*2048 + 512 + d]);
        const float* bc = bc_g + p*64;
        float dtxc = spv*xcv;
        f32x4 Bq[4], Cq[4];
        #pragma unroll
        for (int q = 0; q < 4; ++q) {
            Bq[q] = ((const f32x4*)bc)[q];
            Cq[q] = ((const f32x4*)(bc + 16))[q];
        }
        #pragma unroll
        for (int j = 0; j < 16; ++j) {
            float e = __expf(spv*Ac[j]);
            h[j] = fmaf(e, h[j], dtxc*Bq[j>>2][j&3]);
        }
        float p0 = 0.f, p1 = 0.f, p2 = 0.f, p3 = 0.f;
        #pragma unroll
        for (int q = 0; q < 4; ++q) {
            p0 = fmaf(h[q*4+0], Cq[q][0], p0);
            p1 = fmaf(h[q*4+1], Cq[q][1], p1);
            p2 = fmaf(h[q*4+2], Cq[q][2], p2);
            p3 = fmaf(h[q*4+3], Cq[q][3], p3);
        }
        float dot = (p0 + p1) + (p2 + p3);
        if (t < TT) {
            int tg = rev ? TT-1-t : t;
            float yv = (dot + dp*xcv) * zsv;
            yb[(bbase + tg)*512 + d] = f2bu(yv);
        }
    }
}

// ---------------------------------------------------------------------------
// LayerNorm (up to 3 summed inputs), optional bf16 output
// ---------------------------------------------------------------------------
__global__ __launch_bounds__(64)
void ln_kernel(float* __restrict__ dst, const float* __restrict__ a,
               const float* __restrict__ b, const float* __restrict__ c,
               const float* __restrict__ g, const float* __restrict__ beta,
               ushort* __restrict__ outb)
{
    int row = blockIdx.x;
    int lane = threadIdx.x;
    size_t base = (size_t)row * DD;
    float x[8];
    #pragma unroll
    for (int j = 0; j < 2; ++j) {
        int e4 = j*64 + lane;
        float4 v = *(const float4*)(a + base + (size_t)e4*4);
        if (b) { float4 t = *(const float4*)(b + base + (size_t)e4*4); v.x+=t.x; v.y+=t.y; v.z+=t.z; v.w+=t.w; }
        if (c) { float4 t = *(const float4*)(c + base + (size_t)e4*4); v.x+=t.x; v.y+=t.y; v.z+=t.z; v.w+=t.w; }
        x[j*4+0]=v.x; x[j*4+1]=v.y; x[j*4+2]=v.z; x[j*4+3]=v.w;
    }
    float s = 0.f;
    #pragma unroll
    for (int i = 0; i < 8; ++i) s += x[i];
    #pragma unroll
    for (int m = 1; m < 64; m <<= 1) s += __shfl_xor(s, m);
    float mu = s * (1.f/DD);
    float vs = 0.f;
    #pragma unroll
    for (int i = 0; i < 8; ++i) { float dd = x[i]-mu; vs += dd*dd; }
    #pragma unroll
    for (int m = 1; m < 64; m <<= 1) vs += __shfl_xor(vs, m);
    float r = rsqrtf(vs*(1.f/DD) + 1e-5f);
    #pragma unroll
    for (int j = 0; j < 2; ++j) {
        int e4 = j*64 + lane;
        float4 gv = *(const float4*)(g    + (size_t)e4*4);
        float4 bv = *(const float4*)(beta + (size_t)e4*4);
        float4 o;
        o.x = (x[j*4+0]-mu)*r*gv.x + bv.x;
        o.y = (x[j*4+1]-mu)*r*gv.y + bv.y;
        o.z = (x[j*4+2]-mu)*r*gv.z + bv.z;
        o.w = (x[j*4+3]-mu)*r*gv.w + bv.w;
        *(float4*)(dst + base + (size_t)e4*4) = o;
        if (outb) {
            ushort* ob = outb + (size_t)row*512;
            ob[e4*4+0] = f2bu(o.x);
            ob[e4*4+1] = f2bu(o.y);
            ob[e4*4+2] = f2bu(o.z);
            ob[e4*4+3] = f2bu(o.w);
        }
    }
}

// ---------------------------------------------------------------------------
// proj finish: transpose [b*TT+n][96] -> out[b][p][n], de-normalize.
// ---------------------------------------------------------------------------
__global__ __launch_bounds__(256)
void proj_fin(const float* __restrict__ projtmp, const float* __restrict__ mean,
              const float* __restrict__ stdv, float* __restrict__ out)
{
    int b  = blockIdx.x >> 2;
    int n0 = (blockIdx.x & 3) << 6;
    __shared__ float tile[64][97];
    for (int i = threadIdx.x; i < 64*96; i += 256) {
        int rj = i / 96, cp = i % 96;
        tile[rj][cp] = projtmp[((size_t)b*TT + n0 + rj)*96 + cp];
    }
    __syncthreads();
    int nl = threadIdx.x & 63;
    int pg = threadIdx.x >> 6;          // 0..3
    int n = n0 + nl;
    float sd = stdv[b*NV + n];
    float mu = mean[b*NV + n];
    #pragma unroll
    for (int i = 0; i < 24; ++i) {
        int p = pg*24 + i;
        out[((size_t)b*PRED + p)*NV + n] = tile[nl][p]*sd + mu;
    }
}

// ---------------------------------------------------------------------------
extern "C" void kernel_launch(void* const* d_in, const int* in_sizes, int n_in,
                              void* d_out, int out_size, void* d_ws, size_t ws_size,
                              hipStream_t stream)
{
    (void)in_sizes; (void)n_in; (void)out_size; (void)ws_size;
    const float* x_enc   = (const float*)d_in[0];
    const float* x_mark  = (const float*)d_in[1];
    const float* emb_w   = (const float*)d_in[2];
    const float* emb_b   = (const float*)d_in[3];
    const float* m_win   = (const float*)d_in[4];
    const float* m_convw = (const float*)d_in[5];
    const float* m_convb = (const float*)d_in[6];
    const float* m_wx    = (const float*)d_in[7];
    const float* m_wdt   = (const float*)d_in[8];
    const float* m_bdt   = (const float*)d_in[9];
    const float* m_alog  = (const float*)d_in[10];
    const float* m_dpar  = (const float*)d_in[11];
    const float* m_wout  = (const float*)d_in[12];
    const float* ln1_g   = (const float*)d_in[13];
    const float* ln1_b   = (const float*)d_in[14];
    const float* ff1_w   = (const float*)d_in[15];
    const float* ff1_b   = (const float*)d_in[16];
    const float* ff2_w   = (const float*)d_in[17];
    const float* ff2_b   = (const float*)d_in[18];
    const float* ln2_g   = (const float*)d_in[19];
    const float* ln2_b   = (const float*)d_in[20];
    const float* lnf_g   = (const float*)d_in[21];
    const float* lnf_b   = (const float*)d_in[22];
    const float* proj_w  = (const float*)d_in[23];
    const float* proj_b  = (const float*)d_in[24];
    float* out = (float*)d_out;

    float* ws = (float*)d_ws;
    const size_t NBT = (size_t)MROWS;
    size_t off = 0;
    float* mean = ws + off; off += 8192;
    float* stdv = ws + off; off += 8192;
    ushort* w_emb  = (ushort*)(ws + off); off += 131072;     // 512*512 ush
    ushort* w_win  = (ushort*)(ws + off); off += 1048576;    // 4096*512 ush
    ushort* w_wout = (ushort*)(ws + off); off += 524288;     // 2048*512 ush
    ushort* w_ff1  = (ushort*)(ws + off); off += 262144;     // 1024*512 ush
    ushort* w_ff2  = (ushort*)(ws + off); off += 262144;
    ushort* w_comb = (ushort*)(ws + off); off += 557056;     // 4*544*512 ush
    ushort* w_proj = (ushort*)(ws + off); off += 24576;      // 96*512 ush
    ushort* pool = (ushort*)(ws + off); off += NBT*768;      // tokb | xcb | yb2
    ushort* tokb = pool;                                     // [M][512] ush
    ushort* xcb  = pool;                                     // [M][1024] ush
    ushort* yb   = pool;                                     // [2M][512] ush (row-stacked)
    float* h   = ws + off; off += NBT*512;
    ushort* hb = (ushort*)(ws + off); off += NBT*256;        // [M][512] ush
    ushort* xzb = (ushort*)(ws + off); off += NBT*1024;      // [M][2048] ush
    ushort* fftb = xzb;                                      // alias (xzb dead at ffn)
    ushort* spb = (ushort*)(ws + off); off += NBT*512;       // [M][1024] ush
    float* xc  = ws + off; off += NBT*1024;                  // fp32 [M][1024]
    float* bc2 = ws + off; off += NBT*64;                    // merged [M][64]
    float* fbuf = ws + off; off += NBT*512;                  // fbuf|rbuf contiguous
    float* rbuf = ws + off; off += NBT*512;
    float* hs  = ws + off; off += (size_t)2*(NCHK-1)*65536*4;
    float* psb = ws + off; off += (size_t)2*(NCHK-1)*65536*4;
    float* hin = ws + off; off += (size_t)2*(NCHK-1)*65536*4;
    float* projtmp = ws + off; off += NBT*96;
    (void)rbuf;

    // ---- weight packing: ONE launch for all 6 bf16 casts ----
    packall<<<dim3((4505600+255)/256), 256, 0, stream>>>(
        emb_w, w_emb, m_win, w_win, m_wout, w_wout,
        ff1_w, w_ff1, ff2_w, w_ff2, proj_w, w_proj);
    mkcomb<<<dim3(544,4), 256, 0, stream>>>(m_wx, m_wdt, w_comb);

    stats_kernel<<<dim3(BB*16), 256, 0, stream>>>(x_enc, mean, stdv);
    tok_kernel<<<dim3(BB*40), 256, 0, stream>>>(x_enc, x_mark, mean, stdv, tokb);

    gemm3<1,0,1,1,0><<<dim3(66*8), 256, 0, stream>>>(tokb, 512, w_emb, 512,
        emb_b, h, DD, hb, 512, nullptr, 0,0,0,0,0, MROWS, 512, 512);

    for (int l = 0; l < 2; ++l) {
        // merged win: N=2048 (both dirs), bf16 out
        gemm3<0,0,0,1,0><<<dim3(66*32), 256, 0, stream>>>(hb, 512,
            w_win + (size_t)l*2048*512, 512, nullptr,
            nullptr, 0, xzb, 2048, nullptr, 0,0,0,0,0, MROWS, 2048, 512);
        conv2<<<dim3((2*MROWS*DD)/256), 256, 0, stream>>>(xzb,
            m_convw + (size_t)l*2*DD*2, m_convb + (size_t)l*2*DD, xc, xcb);
        // comb GEMM, both dirs batched: softplus -> bf16 spb (ldc=1024)
        gemm3<0,0,0,0,1><<<dim3(66*9, 2), 256, 0, stream>>>(
            xcb, 1024, w_comb + (size_t)l*2*544*512, 512,
            m_bdt + (size_t)l*2*DD, nullptr, 1024, spb, 64, bc2,
            /*aOff*/512, /*wOff*/(size_t)544*512, /*biasOff*/512,
            /*cOff*/512, /*bcOff*/32, MROWS, 544, 512);
        // scans, 16-state chunked, sp bf16 / xc fp32
        const float* al = m_alog + (size_t)l*2*DD*SS;
        const float* dpp = m_dpar + (size_t)l*2*DD;
        scan_p1<<<dim3(256, NCHK-1, 2), 64, 0, stream>>>(spb, xc, bc2, al,
            hs, psb);
        scan_comb<<<dim3(256, 2), 256, 0, stream>>>(hs, psb, hin);
        scan_p2<<<dim3(256, NCHK, 2), 64, 0, stream>>>(spb, xc, xzb, bc2,
            al, dpp, hin, yb);
        // wout, both dirs batched: A rows stacked, C fbuf|rbuf contiguous
        gemm3<0,0,1,0,0><<<dim3(66*8, 2), 256, 0, stream>>>(yb, 512,
            w_wout + (size_t)l*2*512*512, 512, nullptr,
            fbuf, DD, nullptr, 0, nullptr,
            /*aOff*/NBT*512, /*wOff*/(size_t)512*512, /*biasOff*/0,
            /*cOff*/NBT*512, /*bcOff*/0, MROWS, 512, 512);
        ln_kernel<<<dim3(MROWS), 64, 0, stream>>>(h, h, fbuf, rbuf,
            ln1_g + l*DD, ln1_b + l*DD, hb);
        gemm3<1,1,0,1,0><<<dim3(66*8), 256, 0, stream>>>(hb, 512,
            w_ff1 + (size_t)l*512*512, 512, ff1_b + l*DD,
            nullptr, 0, fftb, 512, nullptr, 0,0,0,0,0, MROWS, 512, 512);
        gemm3<1,0,1,0,0><<<dim3(66*8), 256, 0, stream>>>(fftb, 512,
            w_ff2 + (size_t)l*512*512, 512, ff2_b + l*DD,
            xc, DD, nullptr, 0, nullptr, 0,0,0,0,0, MROWS, 512, 512);
        ln_kernel<<<dim3(MROWS), 64, 0, stream>>>(h, h, xc, nullptr,
            ln2_g + l*DD, ln2_b + l*DD, hb);
    }
    ln_kernel<<<dim3(MROWS), 64, 0, stream>>>(fbuf, h, nullptr, nullptr,
                                              lnf_g, lnf_b, hb);
    gemm3<1,0,1,0,0><<<dim3(66*2), 256, 0, stream>>>(hb, 512, w_proj, 512,
        proj_b, projtmp, 96, nullptr, 0, nullptr, 0,0,0,0,0, MROWS, 96, 512);
    proj_fin<<<dim3(BB*4), 256, 0, stream>>>(projtmp, mean, stdv, out);
}

// Round 37
// 564.587 us; speedup vs baseline: 1.1740x; 1.1050x over previous
//
#include <hip/hip_runtime.h>
#include <hip/hip_bf16.h>
#include <math.h>
#include <stddef.h>

#define BB 32
#define TT 262
#define DD 512
#define SS 16
#define RR 32
#define SEQ 512
#define NV 256
#define PRED 96
#define MROWS (BB*TT)   // 8384
#define NCHK 8
#define CSZ 33          // 8*33 = 264 >= 262

typedef __attribute__((ext_vector_type(4))) float f32x4;
typedef __attribute__((ext_vector_type(8))) short s16x8;

// ---------------- bf16 helpers ----------------
__device__ inline ushort f2bu(float x) {
    __hip_bfloat16 h = __float2bfloat16(x);
    ushort u; __builtin_memcpy(&u, &h, 2); return u;
}
__device__ inline float bu2f(ushort u) {
    __hip_bfloat16 h; __builtin_memcpy(&h, &u, 2);
    return __bfloat162float(h);
}

// async global->LDS, 16B per lane
__device__ inline void gload_lds16(const void* g, void* l) {
    __builtin_amdgcn_global_load_lds(
        (const __attribute__((address_space(1))) void*)g,
        (__attribute__((address_space(3))) void*)l, 16, 0, 0);
}

// ---------------------------------------------------------------------------
// merged weight bf16 cast: all 6 weights in ONE launch.
// wout region is INTERLEAVED: dst[(l*512+n)*1024 + dir*512 + k].
// ---------------------------------------------------------------------------
__global__ __launch_bounds__(256)
void packall(const float* __restrict__ s0, ushort* __restrict__ d0,  // emb 262144
             const float* __restrict__ s1, ushort* __restrict__ d1,  // win 2097152
             const float* __restrict__ s2, ushort* __restrict__ d2,  // wout 1048576 (interleave)
             const float* __restrict__ s3, ushort* __restrict__ d3,  // ff1 524288
             const float* __restrict__ s4, ushort* __restrict__ d4,  // ff2 524288
             const float* __restrict__ s5, ushort* __restrict__ d5)  // proj 49152
{
    int idx = blockIdx.x * 256 + threadIdx.x;
    if (idx >= 4505600) return;
    if (idx >= 2359296 && idx < 3407872) {
        // wout: src (L,2,512,512) -> dst (L,512,1024) with dir in cols
        int o = idx - 2359296;
        int l   = o >> 19;            // /524288
        int rem = o & 524287;
        int dir = rem >> 18;          // /262144
        int n   = (rem >> 9) & 511;
        int k   = rem & 511;
        d2[((size_t)(l*512 + n))*1024 + dir*512 + k] = f2bu(s2[o]);
        return;
    }
    const float* s; ushort* dst; int o;
    if      (idx < 262144)  { s = s0; dst = d0; o = idx; }
    else if (idx < 2359296) { s = s1; dst = d1; o = idx - 262144; }
    else if (idx < 3932160) { s = s3; dst = d3; o = idx - 3407872; }
    else if (idx < 4456448) { s = s4; dst = d4; o = idx - 3932160; }
    else                    { s = s5; dst = d5; o = idx - 4456448; }
    dst[o] = f2bu(s[o]);
}

// ---------------------------------------------------------------------------
// combined scan-projection weight (dt path folded through wdt), bf16
// ---------------------------------------------------------------------------
__global__ __launch_bounds__(256)
void mkcomb(const float* __restrict__ wx, const float* __restrict__ wdt,
            ushort* __restrict__ comb)
{
    int n  = blockIdx.x;
    int li = blockIdx.y;
    const float* wxl = wx + (size_t)li*64*512;
    ushort* outb = comb + ((size_t)li*544 + n)*512;
    if (n < 512) {
        __shared__ float wr[32];
        if (threadIdx.x < 32)
            wr[threadIdx.x] = wdt[(size_t)li*512*32 + (size_t)n*32 + threadIdx.x];
        __syncthreads();
        for (int kk = threadIdx.x; kk < 512; kk += 256) {
            float acc = 0.f;
            #pragma unroll
            for (int r = 0; r < 32; ++r)
                acc = fmaf(wr[r], wxl[r*512 + kk], acc);
            outb[kk] = f2bu(acc);
        }
    } else {
        int s = n - 512;
        for (int kk = threadIdx.x; kk < 512; kk += 256)
            outb[kk] = f2bu(wxl[(32+s)*512 + kk]);
    }
}

// ---------------------------------------------------------------------------
// per-(b,n) mean/std over SEQ. grid = BB*16, block 256 = 16n x 16tg.
// ---------------------------------------------------------------------------
__global__ __launch_bounds__(256)
void stats_kernel(const float* __restrict__ x_enc,
                  float* __restrict__ mean, float* __restrict__ stdv)
{
    int b  = blockIdx.x >> 4;
    int n0 = (blockIdx.x & 15) << 4;
    int nl = threadIdx.x & 15;
    int tg = threadIdx.x >> 4;
    int n = n0 + nl;
    const float* base = x_enc + (size_t)b*SEQ*NV + n;
    float s0 = 0.f, s1 = 0.f, q0 = 0.f, q1 = 0.f;
    #pragma unroll 8
    for (int i = 0; i < 16; ++i) {
        int t = tg + i*32;
        float v0 = base[(size_t)t*NV];
        float v1 = base[(size_t)(t+16)*NV];
        s0 += v0; q0 = fmaf(v0, v0, q0);
        s1 += v1; q1 = fmaf(v1, v1, q1);
    }
    float s = s0 + s1, q = q0 + q1;
    __shared__ float ls[16][17], lq[16][17];
    ls[tg][nl] = s; lq[tg][nl] = q;
    __syncthreads();
    if (tg < 8) { ls[tg][nl] += ls[tg+8][nl]; lq[tg][nl] += lq[tg+8][nl]; }
    __syncthreads();
    if (tg < 4) { ls[tg][nl] += ls[tg+4][nl]; lq[tg][nl] += lq[tg+4][nl]; }
    __syncthreads();
    if (tg < 2) { ls[tg][nl] += ls[tg+2][nl]; lq[tg][nl] += lq[tg+2][nl]; }
    __syncthreads();
    if (tg == 0) {
        s = ls[0][nl] + ls[1][nl];
        q = lq[0][nl] + lq[1][nl];
        float mu  = s * (1.f/SEQ);
        float var = q * (1.f/SEQ) - mu*mu;
        mean[b*NV + n] = mu;
        stdv[b*NV + n] = sqrtf(var + 1e-5f);
    }
}

// ---------------------------------------------------------------------------
// tok: normalized transpose, bf16 rows of 512
// ---------------------------------------------------------------------------
__global__ __launch_bounds__(256)
void tok_kernel(const float* __restrict__ x_enc, const float* __restrict__ x_mark,
                const float* __restrict__ mean, const float* __restrict__ stdv,
                ushort* __restrict__ tokb)
{
    int b  = blockIdx.x / 40;
    int r  = blockIdx.x % 40;
    int tt = r / 5;
    int vt = r % 5;
    int t0 = tt << 6, v0 = vt << 6;
    __shared__ float tile[64][65];
    int lv = threadIdx.x & 63;
    for (int i = threadIdx.x >> 6; i < 64; i += 4) {
        int t = t0 + i, v = v0 + lv;
        float val = 0.f;
        if (v < NV) {
            val = (x_enc[((size_t)b*SEQ + t)*NV + v] - mean[b*NV + v]) / stdv[b*NV + v];
        } else if (v < TT) {
            val = x_mark[((size_t)b*SEQ + t)*6 + (v - NV)];
        }
        tile[i][lv] = val;
    }
    __syncthreads();
    for (int i = threadIdx.x >> 6; i < 64; i += 4) {
        int v = v0 + i;
        if (v < TT) {
            size_t row = (size_t)b*TT + v;
            tokb[row*512 + t0 + lv] = f2bu(tile[lv][i]);
        }
    }
}

// ---------------------------------------------------------------------------
// bf16 MFMA GEMM (NT; K multiple of 64). 128x64 tile, 4 waves (2M x 2N of
// 64x32), double-buffered 48KB LDS. grid = (66 * ntile(Nn), NDIR).
// SCANEP: n<512 -> softplus -> bf16 C3[m*ldc+n]; n>=512 -> bcbuf fp32.
// ---------------------------------------------------------------------------
template<int HAS_BIAS, int RELU, int WF32, int W3, int SCANEP>
__global__ __launch_bounds__(256)
void gemm3(const ushort* __restrict__ A3, int lda3,
           const ushort* __restrict__ W3p, int ldw3,
           const float* __restrict__ bias,
           float* __restrict__ C, int ldc,
           ushort* __restrict__ C3, int N_out,
           float* __restrict__ bcbuf,
           size_t aOff, size_t wOff, size_t biasOff, size_t cOff, size_t bcOff,
           int M, int Nn, int K3)
{
    const int dir = blockIdx.y;
    A3  += (size_t)dir * aOff;
    W3p += (size_t)dir * wOff;
    if (HAS_BIAS || SCANEP) bias += (size_t)dir * biasOff;
    if (WF32) C += (size_t)dir * cOff;
    if (W3 || SCANEP) C3 += (size_t)dir * cOff;
    if (SCANEP) bcbuf += (size_t)dir * bcOff;

    __shared__ ushort lds[2][192*64];   // [buf][A(128x64) | W(64x64)] : 48 KB
    const int tid  = threadIdx.x;
    const int lane = tid & 63;
    const int wid  = tid >> 6;
    const int wr = wid >> 1, wc = wid & 1;

    int nwg = gridDim.x;
    int q8 = nwg >> 3, r8 = nwg & 7;
    int xcd = blockIdx.x & 7;
    int idx = blockIdx.x >> 3;
    int swz = (xcd < r8 ? xcd*(q8+1) : r8*(q8+1) + (xcd-r8)*q8) + idx;
    int ntile = (Nn + 63) >> 6;
    const int m0 = (swz / ntile) * 128;
    const int n0 = (swz % ntile) * 64;

    const int l8 = lane >> 3;
    const int sl = lane & 7;
    const int ssl = sl ^ l8;

    int arow[4], wrow[2];
    #pragma unroll
    for (int qq = 0; qq < 4; ++qq) {
        int r = (wid*4 + qq)*8 + l8;
        int ar = m0 + r; if (ar > M-1) ar = M-1;
        arow[qq] = ar;
    }
    #pragma unroll
    for (int qq = 0; qq < 2; ++qq) {
        int r = (wid*2 + qq)*8 + l8;
        int wrr = n0 + r; if (wrr > Nn-1) wrr = Nn-1;
        wrow[qq] = wrr;
    }

    f32x4 acc[4][2];
    #pragma unroll
    for (int i = 0; i < 4; ++i)
        #pragma unroll
        for (int j = 0; j < 2; ++j) acc[i][j] = (f32x4){0.f,0.f,0.f,0.f};

    const int nk = K3 >> 6;
    const int rl = lane & 15;
    const int kq = lane >> 4;

    auto stage = [&](int buf_, int kt_) {
        #pragma unroll
        for (int qq = 0; qq < 4; ++qq) {
            int c = wid*4 + qq;
            gload_lds16(A3 + (size_t)arow[qq]*lda3 + kt_*64 + ssl*8,
                        (void*)&lds[buf_][c*512]);
        }
        #pragma unroll
        for (int qq = 0; qq < 2; ++qq) {
            int c = wid*2 + qq;
            gload_lds16(W3p + (size_t)wrow[qq]*ldw3 + kt_*64 + ssl*8,
                        (void*)&lds[buf_][8192 + c*512]);
        }
    };

    stage(0, 0);
    __syncthreads();

    for (int kt = 0; kt < nk; ++kt) {
        int cur = kt & 1;
        if (kt + 1 < nk) stage(cur ^ 1, kt + 1);
        #pragma unroll
        for (int kk = 0; kk < 2; ++kk) {
            s16x8 av[4], wv[2];
            #pragma unroll
            for (int mi = 0; mi < 4; ++mi) {
                int row = wr*64 + mi*16 + rl;
                int ck = (kk*4 + kq) ^ (row & 7);
                av[mi] = *(const s16x8*)&lds[cur][row*64 + (ck<<3)];
            }
            #pragma unroll
            for (int ni = 0; ni < 2; ++ni) {
                int row = wc*32 + ni*16 + rl;
                int ck = (kk*4 + kq) ^ (row & 7);
                wv[ni] = *(const s16x8*)&lds[cur][8192 + row*64 + (ck<<3)];
            }
            #pragma unroll
            for (int mi = 0; mi < 4; ++mi)
                #pragma unroll
                for (int ni = 0; ni < 2; ++ni)
                    acc[mi][ni] = __builtin_amdgcn_mfma_f32_16x16x32_bf16(
                        av[mi], wv[ni], acc[mi][ni], 0, 0, 0);
        }
        __syncthreads();
    }

    #pragma unroll
    for (int ni = 0; ni < 2; ++ni) {
        int n = n0 + wc*32 + ni*16 + rl;
        if (n >= Nn) continue;
        float bv = (HAS_BIAS && !SCANEP) ? bias[n] : 0.f;
        #pragma unroll
        for (int mi = 0; mi < 4; ++mi) {
            #pragma unroll
            for (int j = 0; j < 4; ++j) {
                int m = m0 + wr*64 + mi*16 + kq*4 + j;
                if (m >= M) continue;
                float v = acc[mi][ni][j];
                if (SCANEP) {
                    if (n < 512) {
                        v += bias[n];
                        v = fmaxf(v, 0.f) + __logf(1.f + __expf(-fabsf(v)));
                        C3[(size_t)m*ldc + n] = f2bu(v);
                    } else {
                        bcbuf[(size_t)m*N_out + (n - 512)] = v;
                    }
                } else {
                    if (HAS_BIAS) v += bv;
                    if (RELU) v = fmaxf(v, 0.f);
                    if (WF32) C[(size_t)m*ldc + n] = v;
                    if (W3)   C3[(size_t)m*N_out + n] = f2bu(v);
                }
            }
        }
    }
}

// ---------------------------------------------------------------------------
// conv2: both dirs in one launch. xzb bf16 [M][2048]; writes merged xc fp32
// [M][1024], xcb bf16 [M][1024]; silu(z) in place (bf16).
// ---------------------------------------------------------------------------
__global__ __launch_bounds__(256)
void conv2(ushort* __restrict__ xzb, const float* __restrict__ cwB,
           const float* __restrict__ cbB, float* __restrict__ xc,
           ushort* __restrict__ xcb)
{
    int gid = blockIdx.x * 256 + threadIdx.x;   // 2*M*512 exact
    int d = gid & 511;
    int r = gid >> 9;
    int dir = (r >= MROWS) ? 1 : 0;
    int bt = r - dir*MROWS;
    int t = bt % TT;
    const float* cw = cwB + dir*DD*2;
    const float* cb = cbB + dir*DD;
    size_t base = (size_t)bt*2048 + (size_t)dir*1024;
    float cur = bu2f(xzb[base + d]);
    int tn = dir ? t + 1 : t - 1;
    float prev = 0.f;
    if (tn >= 0 && tn < TT)
        prev = bu2f(xzb[base + (dir ? 2048 : -2048) + d]);
    float v = prev*cw[d*2] + cur*cw[d*2+1] + cb[d];
    float sv = v / (1.f + __expf(-v));
    size_t o = (size_t)bt*1024 + dir*512 + d;
    xc[o] = sv;
    xcb[o] = f2bu(sv);
    float z = bu2f(xzb[base + 512 + d]);
    xzb[base + 512 + d] = f2bu(z / (1.f + __expf(-z)));
}

// ---------------------------------------------------------------------------
// Chunked scan pass 1, 16 states/thread. sp bf16 / xc fp32.
// grid (256 = 32b x 8dblk, NCHK-1, 2=dir), block 64.
// ---------------------------------------------------------------------------
__global__ __launch_bounds__(64)
void scan_p1(const ushort* __restrict__ sp_g, const float* __restrict__ xc_g,
             const float* __restrict__ bc_g, const float* __restrict__ alog,
             float* __restrict__ hs, float* __restrict__ ps)
{
    int dir = blockIdx.z;
    int rev = dir;
    sp_g += dir*512; xc_g += dir*512; bc_g += dir*32;
    alog += (size_t)dir*DD*SS;
    size_t doff = (size_t)dir*(NCHK-1)*65536*4;   // floats
    hs += doff; ps += doff;

    int sblk = blockIdx.x;
    int c    = blockIdx.y;
    int b  = sblk >> 3;
    int d  = ((sblk & 7) << 6) + threadIdx.x;

    float Ac[16];
    #pragma unroll
    for (int j = 0; j < 16; ++j)
        Ac[j] = -__expf(alog[d*SS + j]);

    float h[16], pp[16];
    #pragma unroll
    for (int j = 0; j < 16; ++j) { h[j] = 0.f; pp[j] = 1.f; }

    size_t bbase = (size_t)b*TT;
    int t0 = c*CSZ;
    for (int i = 0; i < CSZ; ++i) {
        int t = t0 + i;
        size_t p = bbase + (rev ? TT-1-t : t);
        float spv = bu2f(sp_g[p*1024 + d]);
        float xcv = xc_g[p*1024 + d];
        const float* bc = bc_g + p*64;
        float dtxc = spv*xcv;
        f32x4 Bq[4];
        #pragma unroll
        for (int q = 0; q < 4; ++q) Bq[q] = ((const f32x4*)bc)[q];
        #pragma unroll
        for (int j = 0; j < 16; ++j) {
            float e = __expf(spv*Ac[j]);
            h[j] = fmaf(e, h[j], dtxc*Bq[j>>2][j&3]);
            pp[j] *= e;
        }
    }
    size_t o = (((size_t)c*256 + sblk)*64 + threadIdx.x)*4;   // f4 units
    #pragma unroll
    for (int q = 0; q < 4; ++q) {
        ((f32x4*)hs)[o + q] = (f32x4){h[q*4+0], h[q*4+1], h[q*4+2], h[q*4+3]};
        ((f32x4*)ps)[o + q] = (f32x4){pp[q*4+0], pp[q*4+1], pp[q*4+2], pp[q*4+3]};
    }
}

// ---------------------------------------------------------------------------
// Chunked scan, combine (elementwise over the per-chunk blocks). grid (256,2).
// ---------------------------------------------------------------------------
__global__ __launch_bounds__(256)
void scan_comb(const float* __restrict__ hs, const float* __restrict__ ps,
               float* __restrict__ hin)
{
    int dir = blockIdx.y;
    size_t doff = (size_t)dir*(NCHK-1)*65536;   // in f4 units
    size_t gid = (size_t)blockIdx.x*256 + threadIdx.x;   // 65536
    float4 h = {0.f,0.f,0.f,0.f};
    for (int c = 0; c < NCHK-1; ++c) {
        size_t o = doff + (size_t)c*65536 + gid;
        float4 hl = ((const float4*)hs)[o];
        float4 pv = ((const float4*)ps)[o];
        h.x = fmaf(pv.x, h.x, hl.x);
        h.y = fmaf(pv.y, h.y, hl.y);
        h.z = fmaf(pv.z, h.z, hl.z);
        h.w = fmaf(pv.w, h.w, hl.w);
        ((float4*)hin)[o] = h;
    }
}

// ---------------------------------------------------------------------------
// Chunked scan pass 2, 16 states/thread. sp bf16 / xc fp32 / z bf16.
// grid (256, NCHK, 2), block 64. yb [M][1024]: col offset dir*512.
// ---------------------------------------------------------------------------
__global__ __launch_bounds__(64)
void scan_p2(const ushort* __restrict__ sp_g, const float* __restrict__ xc_g,
             const ushort* __restrict__ xz_u, const float* __restrict__ bc_g,
             const float* __restrict__ alog, const float* __restrict__ dparam,
             const float* __restrict__ hin, ushort* __restrict__ yb)
{
    int dir = blockIdx.z;
    int rev = dir;
    sp_g += dir*512; xc_g += dir*512; bc_g += dir*32; xz_u += dir*1024;
    alog += (size_t)dir*DD*SS; dparam += (size_t)dir*DD;
    hin += (size_t)dir*(NCHK-1)*65536*4;
    yb  += dir*512;

    int sblk = blockIdx.x;
    int c    = blockIdx.y;
    int b  = sblk >> 3;
    int d  = ((sblk & 7) << 6) + threadIdx.x;

    float Ac[16];
    #pragma unroll
    for (int j = 0; j < 16; ++j)
        Ac[j] = -__expf(alog[d*SS + j]);
    float dp = dparam[d];

    float h[16];
    #pragma unroll
    for (int j = 0; j < 16; ++j) h[j] = 0.f;
    if (c > 0) {
        size_t o = (((size_t)(c-1)*256 + sblk)*64 + threadIdx.x)*4;
        #pragma unroll
        for (int q = 0; q < 4; ++q) {
            f32x4 hv = ((const f32x4*)hin)[o + q];
            h[q*4+0]=hv[0]; h[q*4+1]=hv[1]; h[q*4+2]=hv[2]; h[q*4+3]=hv[3];
        }
    }

    size_t bbase = (size_t)b*TT;
    int t0 = c*CSZ;
    for (int i = 0; i < CSZ; ++i) {
        int t = t0 + i;
        int tc = t < TT ? t : TT-1;
        size_t p = bbase + (rev ? TT-1-tc : tc);
        float spv = bu2f(sp_g[p*1024 + d]);
        float xcv = xc_g[p*1024 + d];
        float zsv = bu2f(xz_u[p*2048 + 512 + d]);
        const float* bc = bc_g + p*64;
        float dtxc = spv*xcv;
        f32x4 Bq[4], Cq[4];
        #pragma unroll
        for (int q = 0; q < 4; ++q) {
            Bq[q] = ((const f32x4*)bc)[q];
            Cq[q] = ((const f32x4*)(bc + 16))[q];
        }
        #pragma unroll
        for (int j = 0; j < 16; ++j) {
            float e = __expf(spv*Ac[j]);
            h[j] = fmaf(e, h[j], dtxc*Bq[j>>2][j&3]);
        }
        float p0 = 0.f, p1 = 0.f, p2 = 0.f, p3 = 0.f;
        #pragma unroll
        for (int q = 0; q < 4; ++q) {
            p0 = fmaf(h[q*4+0], Cq[q][0], p0);
            p1 = fmaf(h[q*4+1], Cq[q][1], p1);
            p2 = fmaf(h[q*4+2], Cq[q][2], p2);
            p3 = fmaf(h[q*4+3], Cq[q][3], p3);
        }
        float dot = (p0 + p1) + (p2 + p3);
        if (t < TT) {
            int tg = rev ? TT-1-t : t;
            float yv = (dot + dp*xcv) * zsv;
            yb[(bbase + tg)*1024 + d] = f2bu(yv);
        }
    }
}

// ---------------------------------------------------------------------------
// LayerNorm (up to 3 summed inputs), optional bf16 output
// ---------------------------------------------------------------------------
__global__ __launch_bounds__(64)
void ln_kernel(float* __restrict__ dst, const float* __restrict__ a,
               const float* __restrict__ b, const float* __restrict__ c,
               const float* __restrict__ g, const float* __restrict__ beta,
               ushort* __restrict__ outb)
{
    int row = blockIdx.x;
    int lane = threadIdx.x;
    size_t base = (size_t)row * DD;
    float x[8];
    #pragma unroll
    for (int j = 0; j < 2; ++j) {
        int e4 = j*64 + lane;
        float4 v = *(const float4*)(a + base + (size_t)e4*4);
        if (b) { float4 t = *(const float4*)(b + base + (size_t)e4*4); v.x+=t.x; v.y+=t.y; v.z+=t.z; v.w+=t.w; }
        if (c) { float4 t = *(const float4*)(c + base + (size_t)e4*4); v.x+=t.x; v.y+=t.y; v.z+=t.z; v.w+=t.w; }
        x[j*4+0]=v.x; x[j*4+1]=v.y; x[j*4+2]=v.z; x[j*4+3]=v.w;
    }
    float s = 0.f;
    #pragma unroll
    for (int i = 0; i < 8; ++i) s += x[i];
    #pragma unroll
    for (int m = 1; m < 64; m <<= 1) s += __shfl_xor(s, m);
    float mu = s * (1.f/DD);
    float vs = 0.f;
    #pragma unroll
    for (int i = 0; i < 8; ++i) { float dd = x[i]-mu; vs += dd*dd; }
    #pragma unroll
    for (int m = 1; m < 64; m <<= 1) vs += __shfl_xor(vs, m);
    float r = rsqrtf(vs*(1.f/DD) + 1e-5f);
    #pragma unroll
    for (int j = 0; j < 2; ++j) {
        int e4 = j*64 + lane;
        float4 gv = *(const float4*)(g    + (size_t)e4*4);
        float4 bv = *(const float4*)(beta + (size_t)e4*4);
        float4 o;
        o.x = (x[j*4+0]-mu)*r*gv.x + bv.x;
        o.y = (x[j*4+1]-mu)*r*gv.y + bv.y;
        o.z = (x[j*4+2]-mu)*r*gv.z + bv.z;
        o.w = (x[j*4+3]-mu)*r*gv.w + bv.w;
        *(float4*)(dst + base + (size_t)e4*4) = o;
        if (outb) {
            ushort* ob = outb + (size_t)row*512;
            ob[e4*4+0] = f2bu(o.x);
            ob[e4*4+1] = f2bu(o.y);
            ob[e4*4+2] = f2bu(o.z);
            ob[e4*4+3] = f2bu(o.w);
        }
    }
}

// ---------------------------------------------------------------------------
// proj finish: transpose [b*TT+n][96] -> out[b][p][n], de-normalize.
// ---------------------------------------------------------------------------
__global__ __launch_bounds__(256)
void proj_fin(const float* __restrict__ projtmp, const float* __restrict__ mean,
              const float* __restrict__ stdv, float* __restrict__ out)
{
    int b  = blockIdx.x >> 2;
    int n0 = (blockIdx.x & 3) << 6;
    __shared__ float tile[64][97];
    for (int i = threadIdx.x; i < 64*96; i += 256) {
        int rj = i / 96, cp = i % 96;
        tile[rj][cp] = projtmp[((size_t)b*TT + n0 + rj)*96 + cp];
    }
    __syncthreads();
    int nl = threadIdx.x & 63;
    int pg = threadIdx.x >> 6;          // 0..3
    int n = n0 + nl;
    float sd = stdv[b*NV + n];
    float mu = mean[b*NV + n];
    #pragma unroll
    for (int i = 0; i < 24; ++i) {
        int p = pg*24 + i;
        out[((size_t)b*PRED + p)*NV + n] = tile[nl][p]*sd + mu;
    }
}

// ---------------------------------------------------------------------------
extern "C" void kernel_launch(void* const* d_in, const int* in_sizes, int n_in,
                              void* d_out, int out_size, void* d_ws, size_t ws_size,
                              hipStream_t stream)
{
    (void)in_sizes; (void)n_in; (void)out_size; (void)ws_size;
    const float* x_enc   = (const float*)d_in[0];
    const float* x_mark  = (const float*)d_in[1];
    const float* emb_w   = (const float*)d_in[2];
    const float* emb_b   = (const float*)d_in[3];
    const float* m_win   = (const float*)d_in[4];
    const float* m_convw = (const float*)d_in[5];
    const float* m_convb = (const float*)d_in[6];
    const float* m_wx    = (const float*)d_in[7];
    const float* m_wdt   = (const float*)d_in[8];
    const float* m_bdt   = (const float*)d_in[9];
    const float* m_alog  = (const float*)d_in[10];
    const float* m_dpar  = (const float*)d_in[11];
    const float* m_wout  = (const float*)d_in[12];
    const float* ln1_g   = (const float*)d_in[13];
    const float* ln1_b   = (const float*)d_in[14];
    const float* ff1_w   = (const float*)d_in[15];
    const float* ff1_b   = (const float*)d_in[16];
    const float* ff2_w   = (const float*)d_in[17];
    const float* ff2_b   = (const float*)d_in[18];
    const float* ln2_g   = (const float*)d_in[19];
    const float* ln2_b   = (const float*)d_in[20];
    const float* lnf_g   = (const float*)d_in[21];
    const float* lnf_b   = (const float*)d_in[22];
    const float* proj_w  = (const float*)d_in[23];
    const float* proj_b  = (const float*)d_in[24];
    float* out = (float*)d_out;

    float* ws = (float*)d_ws;
    const size_t NBT = (size_t)MROWS;
    size_t off = 0;
    float* mean = ws + off; off += 8192;
    float* stdv = ws + off; off += 8192;
    ushort* w_emb  = (ushort*)(ws + off); off += 131072;     // 512*512 ush
    ushort* w_win  = (ushort*)(ws + off); off += 1048576;    // 4096*512 ush
    ushort* w_wout = (ushort*)(ws + off); off += 524288;     // 2*512*1024 ush (interleaved)
    ushort* w_ff1  = (ushort*)(ws + off); off += 262144;     // 1024*512 ush
    ushort* w_ff2  = (ushort*)(ws + off); off += 262144;
    ushort* w_comb = (ushort*)(ws + off); off += 557056;     // 4*544*512 ush
    ushort* w_proj = (ushort*)(ws + off); off += 24576;      // 96*512 ush
    ushort* pool = (ushort*)(ws + off); off += NBT*768;      // tokb | xcb | yb
    ushort* tokb = pool;                                     // [M][512] ush
    ushort* xcb  = pool;                                     // [M][1024] ush
    ushort* yb   = pool;                                     // [M][1024] ush (dir in cols)
    float* h   = ws + off; off += NBT*512;
    ushort* hb = (ushort*)(ws + off); off += NBT*256;        // [M][512] ush
    ushort* xzb = (ushort*)(ws + off); off += NBT*1024;      // [M][2048] ush
    ushort* fftb = xzb;                                      // alias (xzb dead at ffn)
    ushort* spb = (ushort*)(ws + off); off += NBT*512;       // [M][1024] ush
    float* xc  = ws + off; off += NBT*1024;                  // fp32 [M][1024]
    float* bc2 = ws + off; off += NBT*64;                    // merged [M][64]
    float* fbuf = ws + off; off += NBT*512;
    float* hs  = ws + off; off += (size_t)2*(NCHK-1)*65536*4;
    float* psb = ws + off; off += (size_t)2*(NCHK-1)*65536*4;
    float* hin = ws + off; off += (size_t)2*(NCHK-1)*65536*4;
    float* projtmp = ws + off; off += NBT*96;

    // ---- weight packing: ONE launch for all 6 bf16 casts ----
    packall<<<dim3((4505600+255)/256), 256, 0, stream>>>(
        emb_w, w_emb, m_win, w_win, m_wout, w_wout,
        ff1_w, w_ff1, ff2_w, w_ff2, proj_w, w_proj);
    mkcomb<<<dim3(544,4), 256, 0, stream>>>(m_wx, m_wdt, w_comb);

    stats_kernel<<<dim3(BB*16), 256, 0, stream>>>(x_enc, mean, stdv);
    tok_kernel<<<dim3(BB*40), 256, 0, stream>>>(x_enc, x_mark, mean, stdv, tokb);

    gemm3<1,0,1,1,0><<<dim3(66*8), 256, 0, stream>>>(tokb, 512, w_emb, 512,
        emb_b, h, DD, hb, 512, nullptr, 0,0,0,0,0, MROWS, 512, 512);

    for (int l = 0; l < 2; ++l) {
        // merged win: N=2048 (both dirs), bf16 out
        gemm3<0,0,0,1,0><<<dim3(66*32), 256, 0, stream>>>(hb, 512,
            w_win + (size_t)l*2048*512, 512, nullptr,
            nullptr, 0, xzb, 2048, nullptr, 0,0,0,0,0, MROWS, 2048, 512);
        conv2<<<dim3((2*MROWS*DD)/256), 256, 0, stream>>>(xzb,
            m_convw + (size_t)l*2*DD*2, m_convb + (size_t)l*2*DD, xc, xcb);
        // comb GEMM, both dirs batched: softplus -> bf16 spb (ldc=1024)
        gemm3<0,0,0,0,1><<<dim3(66*9, 2), 256, 0, stream>>>(
            xcb, 1024, w_comb + (size_t)l*2*544*512, 512,
            m_bdt + (size_t)l*2*DD, nullptr, 1024, spb, 64, bc2,
            /*aOff*/512, /*wOff*/(size_t)544*512, /*biasOff*/512,
            /*cOff*/512, /*bcOff*/32, MROWS, 544, 512);
        // scans, 16-state chunked, sp bf16 / xc fp32; yb [M][1024]
        const float* al = m_alog + (size_t)l*2*DD*SS;
        const float* dpp = m_dpar + (size_t)l*2*DD;
        scan_p1<<<dim3(256, NCHK-1, 2), 64, 0, stream>>>(spb, xc, bc2, al,
            hs, psb);
        scan_comb<<<dim3(256, 2), 256, 0, stream>>>(hs, psb, hin);
        scan_p2<<<dim3(256, NCHK, 2), 64, 0, stream>>>(spb, xc, xzb, bc2,
            al, dpp, hin, yb);
        // wout merged: [y_f|y_r] @ [Wf|Wr]^T, K=1024, single launch
        gemm3<0,0,1,0,0><<<dim3(66*8), 256, 0, stream>>>(yb, 1024,
            w_wout + (size_t)l*512*1024, 1024, nullptr,
            fbuf, DD, nullptr, 0, nullptr,
            0,0,0,0,0, MROWS, 512, 1024);
        ln_kernel<<<dim3(MROWS), 64, 0, stream>>>(h, h, fbuf, nullptr,
            ln1_g + l*DD, ln1_b + l*DD, hb);
        gemm3<1,1,0,1,0><<<dim3(66*8), 256, 0, stream>>>(hb, 512,
            w_ff1 + (size_t)l*512*512, 512, ff1_b + l*DD,
            nullptr, 0, fftb, 512, nullptr, 0,0,0,0,0, MROWS, 512, 512);
        gemm3<1,0,1,0,0><<<dim3(66*8), 256, 0, stream>>>(fftb, 512,
            w_ff2 + (size_t)l*512*512, 512, ff2_b + l*DD,
            xc, DD, nullptr, 0, nullptr, 0,0,0,0,0, MROWS, 512, 512);
        ln_kernel<<<dim3(MROWS), 64, 0, stream>>>(h, h, xc, nullptr,
            ln2_g + l*DD, ln2_b + l*DD, hb);
    }
    ln_kernel<<<dim3(MROWS), 64, 0, stream>>>(fbuf, h, nullptr, nullptr,
                                              lnf_g, lnf_b, hb);
    gemm3<1,0,1,0,0><<<dim3(66*2), 256, 0, stream>>>(hb, 512, w_proj, 512,
        proj_b, projtmp, 96, nullptr, 0, nullptr, 0,0,0,0,0, MROWS, 96, 512);
    proj_fin<<<dim3(BB*4), 256, 0, stream>>>(projtmp, mean, stdv, out);
}